// Round 5
// baseline (331.860 us; speedup 1.0000x reference)
//
#include <hip/hip_runtime.h>
#include <cstdint>
#include <cstddef>

// ---------- types ----------
typedef __attribute__((ext_vector_type(8))) short short8;
typedef __attribute__((ext_vector_type(4))) short short4v;
typedef __attribute__((ext_vector_type(4))) float f32x4;

#define Bdim 2
#define Tdim 2048
#define Cdim 1024
#define Hdim 16
#define HDdim 64
#define Mdim (Bdim*Tdim)   // 4096
#define FFdim (4*Cdim)     // 4096

__device__ __forceinline__ uint16_t f2bf(float f) {
    union { float f; uint32_t u; } v; v.f = f;
    uint32_t x = v.u;
    uint32_t r = x + 0x7FFFu + ((x >> 16) & 1u);
    return (uint16_t)(r >> 16);
}
__device__ __forceinline__ float bf2f(uint16_t h) {
    union { float f; uint32_t u; } v; v.u = ((uint32_t)h) << 16; return v.f;
}

// async global->LDS, 16B per lane. dst must be wave-uniform base; HW adds lane*16.
__device__ __forceinline__ void gload_lds16(const uint16_t* g, uint16_t* l) {
    __builtin_amdgcn_global_load_lds(
        (const __attribute__((address_space(1))) void*)g,
        (__attribute__((address_space(3))) void*)l, 16, 0, 0);
}

// ---------- elementwise cast f32 -> bf16 (vectorized x4) ----------
__global__ __launch_bounds__(256) void cast4_k(const float* __restrict__ in,
                                               uint16_t* __restrict__ out) {
    int i = (blockIdx.x * 256 + threadIdx.x) * 4;
    f32x4 v = *(const f32x4*)(in + i);
    short4v o;
#pragma unroll
    for (int j = 0; j < 4; ++j) o[j] = (short)f2bf(v[j]);
    *(short4v*)(out + i) = o;
}

// ---------- tiled transpose f32(R x Cc) -> bf16(Cc x R), batched ----------
__global__ __launch_bounds__(256) void transpose_tile(const float* __restrict__ in,
                                                      uint16_t* __restrict__ out,
                                                      int R, int Cc,
                                                      size_t ibs, size_t obs) {
    __shared__ uint16_t tile[32][33];
    const float* ip = in + (size_t)blockIdx.z * ibs;
    uint16_t* op = out + (size_t)blockIdx.z * obs;
    int r0 = blockIdx.x * 32, n0 = blockIdx.y * 32;
    int tx = threadIdx.x, ty = threadIdx.y;
#pragma unroll
    for (int i = 0; i < 4; ++i) {
        int r = ty + 8 * i;
        tile[r][tx] = f2bf(ip[(size_t)(r0 + r) * Cc + n0 + tx]);
    }
    __syncthreads();
#pragma unroll
    for (int i = 0; i < 4; ++i) {
        int n = ty + 8 * i;
        op[(size_t)(n0 + n) * R + r0 + tx] = tile[tx][n];
    }
}

// ---------- per-head V transpose: qkv V slice -> vT[bh][d=64][t=T] bf16 ----------
__global__ __launch_bounds__(256) void vtrans_k(const uint16_t* __restrict__ qkv,
                                                uint16_t* __restrict__ vT) {
    __shared__ uint16_t tile[32][33];
    const int bh = blockIdx.z, b = bh >> 4, h = bh & 15;
    const uint16_t* vp = qkv + (size_t)b * Tdim * (3 * Cdim) + 2 * Cdim + h * HDdim;
    uint16_t* op = vT + (size_t)bh * HDdim * Tdim;
    const int t0 = blockIdx.x * 32, d0 = blockIdx.y * 32;
    const int tx = threadIdx.x, ty = threadIdx.y;
#pragma unroll
    for (int i = 0; i < 4; ++i) {
        int r = ty + 8 * i;
        tile[r][tx] = vp[(size_t)(t0 + r) * (3 * Cdim) + d0 + tx];
    }
    __syncthreads();
#pragma unroll
    for (int i = 0; i < 4; ++i) {
        int d = ty + 8 * i;
        op[(size_t)(d0 + d) * Tdim + t0 + tx] = tile[tx][d];
    }
}

// ---------- bf16 MFMA GEMM: C = A(M x Kfull) * Bt(N x Kfull)^T, fp32 accum ----
// Double-buffered prefetch, 1 barrier/K-step. Optional split-K over blockIdx.z:
// each z-slice covers Kp columns; kz=0 applies bias/relu/residual and writes
// outF/outB; kz>0 writes raw fp32 partial to outP (consumer sums).
// XCD-aware bijective swizzle over the whole grid (total % 8 == 0 required).
template<bool BIAS, bool RELU, bool RESID, bool OUTF>
__global__ __launch_bounds__(256) void gemm_k(const uint16_t* __restrict__ A,
                                              const uint16_t* __restrict__ Bt,
                                              int Kfull, int Kp,
                                              float* outF,              // no restrict: may alias resid
                                              uint16_t* __restrict__ outB,
                                              const float* __restrict__ bias,
                                              const float* resid,       // no restrict: may alias outF
                                              float* __restrict__ outP,
                                              int N) {
    __shared__ uint16_t As[2][128 * 32];
    __shared__ uint16_t Bs[2][128 * 32];
    // --- XCD swizzle: contiguous logical-tile chunk per XCD (T1, m204) ---
    const int gx = gridDim.x, gy = gridDim.y;
    const int total = gx * gy * gridDim.z;
    const int orig = blockIdx.x + gx * (blockIdx.y + gy * blockIdx.z);
    const int w = (orig & 7) * (total >> 3) + (orig >> 3);
    const int bx = w % gx;
    const int t2 = w / gx;
    const int by = t2 % gy;
    const int kz = t2 / gy;

    const int tid = threadIdx.x;
    const int wave = tid >> 6, lane = tid & 63;
    const int lg = lane >> 4, lr = lane & 15;
    const int wm = (wave >> 1) << 6, wn = (wave & 1) << 6;
    const uint16_t* ag = A + (size_t)bx * 128 * Kfull + (size_t)(tid >> 2) * Kfull + (tid & 3) * 8 + (size_t)kz * Kp;
    const uint16_t* bg = Bt + (size_t)by * 128 * Kfull + (size_t)(tid >> 2) * Kfull + (tid & 3) * 8 + (size_t)kz * Kp;
    const size_t rstep = (size_t)64 * Kfull;
    const int db0 = wave * 512, db1 = 2048 + wave * 512;   // wave-uniform LDS offsets

    f32x4 acc[4][4];
#pragma unroll
    for (int i = 0; i < 4; ++i)
#pragma unroll
        for (int j = 0; j < 4; ++j) acc[i][j] = (f32x4){0.f, 0.f, 0.f, 0.f};

#define GSTAGE(bi, kk)                                     \
    do {                                                   \
        gload_lds16(ag + (kk), &As[bi][db0]);              \
        gload_lds16(ag + (kk) + rstep, &As[bi][db1]);      \
        gload_lds16(bg + (kk), &Bs[bi][db0]);              \
        gload_lds16(bg + (kk) + rstep, &Bs[bi][db1]);      \
    } while (0)

    GSTAGE(0, 0);
    __syncthreads();
    int cur = 0;
    for (int k0 = 0; k0 < Kp; k0 += 32) {
        if (k0 + 32 < Kp) GSTAGE(cur ^ 1, k0 + 32);
        short8 af[4], bfr[4];
#pragma unroll
        for (int m = 0; m < 4; ++m) af[m] = *(const short8*)(&As[cur][0] + (wm + 16 * m + lr) * 32 + 8 * lg);
#pragma unroll
        for (int n = 0; n < 4; ++n) bfr[n] = *(const short8*)(&Bs[cur][0] + (wn + 16 * n + lr) * 32 + 8 * lg);
#pragma unroll
        for (int m = 0; m < 4; ++m)
#pragma unroll
            for (int n = 0; n < 4; ++n)
                acc[m][n] = __builtin_amdgcn_mfma_f32_16x16x32_bf16(af[m], bfr[n], acc[m][n], 0, 0, 0);
        __syncthreads();
        cur ^= 1;
    }
#undef GSTAGE
    // epilogue: C/D layout col=lane&15, row=4*(lane>>4)+reg  [verified m89/m91]
    if (kz == 0) {
#pragma unroll
        for (int n = 0; n < 4; ++n) {
            const int col = (by << 7) + wn + 16 * n + lr;
            const float bv = BIAS ? bias[col] : 0.f;
#pragma unroll
            for (int m = 0; m < 4; ++m) {
#pragma unroll
                for (int r = 0; r < 4; ++r) {
                    const int row = (bx << 7) + wm + 16 * m + 4 * lg + r;
                    float v = acc[m][n][r] + bv;
                    if (RELU) v = fmaxf(v, 0.f);
                    if (RESID) v += resid[(size_t)row * N + col];
                    if (OUTF) outF[(size_t)row * N + col] = v;
                    else      outB[(size_t)row * N + col] = f2bf(v);
                }
            }
        }
    } else {
#pragma unroll
        for (int n = 0; n < 4; ++n) {
            const int col = (by << 7) + wn + 16 * n + lr;
#pragma unroll
            for (int m = 0; m < 4; ++m) {
#pragma unroll
                for (int r = 0; r < 4; ++r) {
                    const int row = (bx << 7) + wm + 16 * m + 4 * lg + r;
                    outP[(size_t)row * N + col] = acc[m][n][r];
                }
            }
        }
    }
}

// ---------- flash attention, 4-wave blocks, LDS-staged K/V, balanced pairing ----
__global__ __launch_bounds__(256) void attn_k(const uint16_t* __restrict__ qkv,
                                              const uint16_t* __restrict__ vT,
                                              uint16_t* __restrict__ o) {
    __shared__ uint16_t Kb[2][64 * 64];
    __shared__ uint16_t Vb[2][64 * 64];
    const int tid = threadIdx.x;
    const int wave = tid >> 6, lane = tid & 63;
    const int lg = lane >> 4, lr = lane & 15;
    const int bh = blockIdx.y, b = bh >> 4, h = bh & 15;
    const size_t rs = 3 * Cdim;
    const uint16_t* qp = qkv + (size_t)b * Tdim * rs + (size_t)h * HDdim;
    const uint16_t* kp = qp + Cdim;
    const uint16_t* vtp = vT + (size_t)bh * HDdim * Tdim;

    const int s0 = tid, s1 = tid + 256;
    const int r0v = s0 >> 3, c0v = ((s0 & 7) ^ (r0v & 7)) << 3;
    const int r1v = s1 >> 3, c1v = ((s1 & 7) ^ (r1v & 7)) << 3;
    const int db0 = wave * 512, db1 = 2048 + wave * 512;

#define STAGE(bufi, kvb)                                                        \
    do {                                                                        \
        gload_lds16(kp + (size_t)((kvb) + r0v) * rs + c0v, &Kb[bufi][db0]);     \
        gload_lds16(kp + (size_t)((kvb) + r1v) * rs + c1v, &Kb[bufi][db1]);     \
        gload_lds16(vtp + (size_t)r0v * Tdim + (kvb) + c0v, &Vb[bufi][db0]);    \
        gload_lds16(vtp + (size_t)r1v * Tdim + (kvb) + c1v, &Vb[bufi][db1]);    \
    } while (0)

    const int tiles[2] = {(int)blockIdx.x, 31 - (int)blockIdx.x};

    for (int ti = 0; ti < 2; ++ti) {
        const int tx = tiles[ti];
        const int q0 = tx << 6;
        const int nch = tx + 1;
        const int qrow = q0 + 16 * wave + lr;

        short8 qf[2];
#pragma unroll
        for (int c = 0; c < 2; ++c) {
            short8 raw = *(const short8*)(qp + (size_t)qrow * rs + 32 * c + 8 * lg);
#pragma unroll
            for (int j = 0; j < 8; ++j)
                qf[c][j] = (short)f2bf(bf2f((uint16_t)raw[j]) * 0.125f);
        }

        float m_run = -__builtin_inff(), l_run = 0.f;
        f32x4 oacc[4];
#pragma unroll
        for (int t = 0; t < 4; ++t) oacc[t] = (f32x4){0.f, 0.f, 0.f, 0.f};

        STAGE(0, 0);
        __syncthreads();
        int cur = 0;
        for (int ch = 0; ch < nch; ++ch) {
            if (ch + 1 < nch) STAGE(cur ^ 1, 64 * (ch + 1));
            const int kvb = 64 * ch;
            const char* Kc = (const char*)&Kb[cur][0];
            const char* Vc = (const char*)&Vb[cur][0];
            short8 kf[4][2];
#pragma unroll
            for (int u = 0; u < 4; ++u)
#pragma unroll
                for (int c = 0; c < 2; ++c)
                    kf[u][c] = *(const short8*)(Kc + (16 * u + lr) * 128 +
                                                (((lg + 4 * c) ^ (lr & 7)) << 4));
            f32x4 s4[4];
            __builtin_amdgcn_s_setprio(1);
#pragma unroll
            for (int u = 0; u < 4; ++u) {
                f32x4 z = (f32x4){0.f, 0.f, 0.f, 0.f};
                z = __builtin_amdgcn_mfma_f32_16x16x32_bf16(kf[u][0], qf[0], z, 0, 0, 0);
                z = __builtin_amdgcn_mfma_f32_16x16x32_bf16(kf[u][1], qf[1], z, 0, 0, 0);
                s4[u] = z;
            }
            __builtin_amdgcn_s_setprio(0);
            float p[4][4];
            float mx = -__builtin_inff();
#pragma unroll
            for (int u = 0; u < 4; ++u)
#pragma unroll
                for (int r = 0; r < 4; ++r) {
                    int kv = kvb + 16 * u + 4 * lg + r;
                    float sv = (kv <= qrow) ? s4[u][r] : -__builtin_inff();
                    p[u][r] = sv;
                    mx = fmaxf(mx, sv);
                }
            mx = fmaxf(mx, __shfl_xor(mx, 16));
            mx = fmaxf(mx, __shfl_xor(mx, 32));
            const float m_new = fmaxf(m_run, mx);
            const float alpha = __expf(m_run - m_new);
            float ps = 0.f;
#pragma unroll
            for (int u = 0; u < 4; ++u)
#pragma unroll
                for (int r = 0; r < 4; ++r) {
                    float e = __expf(p[u][r] - m_new);
                    p[u][r] = e; ps += e;
                }
            ps += __shfl_xor(ps, 16);
            ps += __shfl_xor(ps, 32);
            l_run = l_run * alpha + ps;
            m_run = m_new;
            short8 pb[2];
#pragma unroll
            for (int hh = 0; hh < 2; ++hh)
#pragma unroll
                for (int j = 0; j < 4; ++j) {
                    pb[hh][j]     = (short)f2bf(p[2 * hh][j]);
                    pb[hh][j + 4] = (short)f2bf(p[2 * hh + 1][j]);
                }
            __builtin_amdgcn_s_setprio(1);
#pragma unroll
            for (int t = 0; t < 4; ++t) {
                f32x4 oa = oacc[t];
#pragma unroll
                for (int r = 0; r < 4; ++r) oa[r] *= alpha;
                const int vbase = (16 * t + lr) * 128;
                const int sw = (lr & 7) << 4;
#pragma unroll
                for (int hh = 0; hh < 2; ++hh) {
                    short4v v0 = *(const short4v*)(Vc + vbase + ((64 * hh + 8 * lg) ^ sw));
                    short4v v1 = *(const short4v*)(Vc + vbase + ((64 * hh + 32 + 8 * lg) ^ sw));
                    short8 vf = (short8){v0[0], v0[1], v0[2], v0[3], v1[0], v1[1], v1[2], v1[3]};
                    oa = __builtin_amdgcn_mfma_f32_16x16x32_bf16(vf, pb[hh], oa, 0, 0, 0);
                }
                oacc[t] = oa;
            }
            __builtin_amdgcn_s_setprio(0);
            __syncthreads();
            cur ^= 1;
        }
        const float inv = 1.f / l_run;
        uint16_t* orow = o + (size_t)(b * Tdim + qrow) * Cdim + h * HDdim;
#pragma unroll
        for (int t = 0; t < 4; ++t)
#pragma unroll
            for (int r = 0; r < 4; ++r)
                orow[16 * t + 4 * lg + r] = f2bf(oacc[t][r] * inv);
        __syncthreads();
    }
#undef STAGE
}

// ---------- LayerNorm over rows of 1024: in (+ optional in2) summed ----------
__global__ __launch_bounds__(256) void ln_k(const float* __restrict__ in,
                                            const float* __restrict__ in2,
                                            const float* __restrict__ g,
                                            const float* __restrict__ be,
                                            float* __restrict__ outF,
                                            uint16_t* __restrict__ outB) {
    const int row = blockIdx.x, tid = threadIdx.x;
    const size_t base = (size_t)row * Cdim + tid * 4;
    f32x4 xv = *(const f32x4*)(in + base);
    if (in2) {
        f32x4 yv = *(const f32x4*)(in2 + base);
#pragma unroll
        for (int j = 0; j < 4; ++j) xv[j] += yv[j];
    }
    float s = xv[0] + xv[1] + xv[2] + xv[3];
    float q = xv[0] * xv[0] + xv[1] * xv[1] + xv[2] * xv[2] + xv[3] * xv[3];
#pragma unroll
    for (int off = 1; off < 64; off <<= 1) { s += __shfl_xor(s, off); q += __shfl_xor(q, off); }
    __shared__ float sm[4], sq[4];
    if ((tid & 63) == 0) { sm[tid >> 6] = s; sq[tid >> 6] = q; }
    __syncthreads();
    s = sm[0] + sm[1] + sm[2] + sm[3];
    q = sq[0] + sq[1] + sq[2] + sq[3];
    const float mu = s * (1.f / 1024.f);
    const float var = q * (1.f / 1024.f) - mu * mu;
    const float rstd = rsqrtf(var + 1e-5f);
#pragma unroll
    for (int j = 0; j < 4; ++j) {
        int col = tid * 4 + j;
        float y = (xv[j] - mu) * rstd * g[col] + be[col];
        if (outF) outF[(size_t)row * Cdim + col] = y;
        if (outB) outB[(size_t)row * Cdim + col] = f2bf(y);
    }
}

// ---------- launch ----------
extern "C" void kernel_launch(void* const* d_in, const int* in_sizes, int n_in,
                              void* d_out, int out_size, void* d_ws, size_t ws_size,
                              hipStream_t stream) {
    const float* x   = (const float*)d_in[0];
    const float* Wq  = (const float*)d_in[1];
    const float* Wk  = (const float*)d_in[2];
    const float* Wv  = (const float*)d_in[3];
    const float* Wp  = (const float*)d_in[4];
    const float* bp  = (const float*)d_in[5];
    const float* W1  = (const float*)d_in[6];
    const float* b1  = (const float*)d_in[7];
    const float* W2  = (const float*)d_in[8];
    const float* b2  = (const float*)d_in[9];
    const float* g1  = (const float*)d_in[10];
    const float* be1 = (const float*)d_in[11];
    const float* g2  = (const float*)d_in[12];
    const float* be2 = (const float*)d_in[13];
    float* out = (float*)d_out;

    // workspace layout (96 MB total), live-range aliased:
    //  [ 0,24M)  qkv (steps 2-4)   | P1p fp32 proj partial (5-6) | h1 [0,32M) (7-8)
    //  [24,32M)  obuf (4-5)        | (h1 tail)
    //  [32,40M)  xb (1-2) | vT (3-4) | x1b (6-7)
    //  [40,46M)  wqkv (1-2)
    //  [46,48M)  wpt (1-5)
    //  [48,64M)  resid = proj out (5-6) | Q1 fp32 FFN2 partial (8-9)
    //  [64,80M)  x1f (6-8), FFN2 kz0 adds in place (8), LN2 reads (9)
    //  [80,88M)  w1t (1-7)
    //  [88,96M)  w2t (1-8)
    char* ws = (char*)d_ws;
    uint16_t* qkv   = (uint16_t*)(ws + 0);
    float*    P1p   = (float*)   (ws + 0);
    uint16_t* h1    = (uint16_t*)(ws + 0);
    uint16_t* obuf  = (uint16_t*)(ws + 25165824);
    uint16_t* xb    = (uint16_t*)(ws + 33554432);
    uint16_t* vT    = (uint16_t*)(ws + 33554432);
    uint16_t* x1b   = (uint16_t*)(ws + 33554432);
    uint16_t* wqkv  = (uint16_t*)(ws + 41943040);
    uint16_t* wpt   = (uint16_t*)(ws + 48234496);
    float*    resid = (float*)   (ws + 50331648);
    float*    Q1    = (float*)   (ws + 50331648);
    float*    x1f   = (float*)   (ws + 67108864);
    uint16_t* w1t   = (uint16_t*)(ws + 83886080);
    uint16_t* w2t   = (uint16_t*)(ws + 92274688);

    // step 1: pack / cast
    cast4_k<<<4096, 256, 0, stream>>>(x, xb);
    transpose_tile<<<dim3(32, 2, 16), dim3(32, 8), 0, stream>>>(Wq, wqkv,           1024, 64, 65536, 65536);
    transpose_tile<<<dim3(32, 2, 16), dim3(32, 8), 0, stream>>>(Wk, wqkv + 1048576, 1024, 64, 65536, 65536);
    transpose_tile<<<dim3(32, 2, 16), dim3(32, 8), 0, stream>>>(Wv, wqkv + 2097152, 1024, 64, 65536, 65536);
    transpose_tile<<<dim3(32, 32, 1),  dim3(32, 8), 0, stream>>>(Wp, wpt, 1024, 1024, 0, 0);
    transpose_tile<<<dim3(32, 128, 1), dim3(32, 8), 0, stream>>>(W1, w1t, 1024, 4096, 0, 0);
    transpose_tile<<<dim3(128, 32, 1), dim3(32, 8), 0, stream>>>(W2, w2t, 4096, 1024, 0, 0);

    // step 2: QKV projection (768 blocks = 3/CU)
    gemm_k<false, false, false, false><<<dim3(32, 24, 1), 256, 0, stream>>>(
        xb, wqkv, Cdim, Cdim, nullptr, qkv, nullptr, nullptr, nullptr, 3 * Cdim);
    // step 3: V^T pack
    vtrans_k<<<dim3(64, 2, 32), dim3(32, 8), 0, stream>>>(qkv, vT);
    // step 4: attention
    attn_k<<<dim3(16, 32), 256, 0, stream>>>(qkv, vT, obuf);
    // step 5: output projection, split-K=2 (512 blocks = 2/CU):
    //   kz=0 -> resid = partial + bp + x ; kz=1 -> P1p raw partial
    gemm_k<true, false, true, true><<<dim3(32, 8, 2), 256, 0, stream>>>(
        obuf, wpt, Cdim, Cdim / 2, resid, nullptr, bp, x, P1p, Cdim);
    // step 6: LN1 over (resid + P1p) -> x1f (fp32) + x1b (bf16)
    ln_k<<<Mdim, 256, 0, stream>>>(resid, P1p, g1, be1, x1f, x1b);
    // step 7: FFN1 relu(x1 @ W1 + b1) -> h1 (1024 blocks = 4/CU)
    gemm_k<true, true, false, false><<<dim3(32, 32, 1), 256, 0, stream>>>(
        x1b, w1t, Cdim, Cdim, nullptr, h1, b1, nullptr, nullptr, FFdim);
    // step 8: FFN2, split-K=2 (512 blocks = 2/CU):
    //   kz=0 -> x1f += partial + b2 (in-place, per-thread exclusive RMW)
    //   kz=1 -> Q1 raw partial
    gemm_k<true, false, true, true><<<dim3(32, 8, 2), 256, 0, stream>>>(
        h1, w2t, FFdim, FFdim / 2, x1f, nullptr, b2, x1f, Q1, Cdim);
    // step 9: LN2 over (x1f + Q1) -> out
    ln_k<<<Mdim, 256, 0, stream>>>(x1f, Q1, g2, be2, out, nullptr);
}

// Round 6
// 311.181 us; speedup vs baseline: 1.0665x; 1.0665x over previous
//
#include <hip/hip_runtime.h>
#include <cstdint>
#include <cstddef>

// ---------- types ----------
typedef __attribute__((ext_vector_type(8))) short short8;
typedef __attribute__((ext_vector_type(4))) short short4v;
typedef __attribute__((ext_vector_type(4))) float f32x4;

#define Bdim 2
#define Tdim 2048
#define Cdim 1024
#define Hdim 16
#define HDdim 64
#define Mdim (Bdim*Tdim)   // 4096
#define FFdim (4*Cdim)     // 4096

__device__ __forceinline__ uint16_t f2bf(float f) {
    union { float f; uint32_t u; } v; v.f = f;
    uint32_t x = v.u;
    uint32_t r = x + 0x7FFFu + ((x >> 16) & 1u);
    return (uint16_t)(r >> 16);
}
__device__ __forceinline__ float bf2f(uint16_t h) {
    union { float f; uint32_t u; } v; v.u = ((uint32_t)h) << 16; return v.f;
}

// async global->LDS, 16B per lane. dst must be wave-uniform base; HW adds lane*16.
__device__ __forceinline__ void gload_lds16(const uint16_t* g, uint16_t* l) {
    __builtin_amdgcn_global_load_lds(
        (const __attribute__((address_space(1))) void*)g,
        (__attribute__((address_space(3))) void*)l, 16, 0, 0);
}

// ---------- elementwise cast f32 -> bf16 (vectorized x4) ----------
__global__ __launch_bounds__(256) void cast4_k(const float* __restrict__ in,
                                               uint16_t* __restrict__ out) {
    int i = (blockIdx.x * 256 + threadIdx.x) * 4;
    f32x4 v = *(const f32x4*)(in + i);
    short4v o;
#pragma unroll
    for (int j = 0; j < 4; ++j) o[j] = (short)f2bf(v[j]);
    *(short4v*)(out + i) = o;
}

// ---------- tiled transpose f32(R x Cc) -> bf16(Cc x R), batched ----------
__global__ __launch_bounds__(256) void transpose_tile(const float* __restrict__ in,
                                                      uint16_t* __restrict__ out,
                                                      int R, int Cc,
                                                      size_t ibs, size_t obs) {
    __shared__ uint16_t tile[32][33];
    const float* ip = in + (size_t)blockIdx.z * ibs;
    uint16_t* op = out + (size_t)blockIdx.z * obs;
    int r0 = blockIdx.x * 32, n0 = blockIdx.y * 32;
    int tx = threadIdx.x, ty = threadIdx.y;
#pragma unroll
    for (int i = 0; i < 4; ++i) {
        int r = ty + 8 * i;
        tile[r][tx] = f2bf(ip[(size_t)(r0 + r) * Cc + n0 + tx]);
    }
    __syncthreads();
#pragma unroll
    for (int i = 0; i < 4; ++i) {
        int n = ty + 8 * i;
        op[(size_t)(n0 + n) * R + r0 + tx] = tile[tx][n];
    }
}

// ---------- per-head V transpose: qkv V slice -> vT[bh][d=64][t=T] bf16 ----------
__global__ __launch_bounds__(256) void vtrans_k(const uint16_t* __restrict__ qkv,
                                                uint16_t* __restrict__ vT) {
    __shared__ uint16_t tile[32][33];
    const int bh = blockIdx.z, b = bh >> 4, h = bh & 15;
    const uint16_t* vp = qkv + (size_t)b * Tdim * (3 * Cdim) + 2 * Cdim + h * HDdim;
    uint16_t* op = vT + (size_t)bh * HDdim * Tdim;
    const int t0 = blockIdx.x * 32, d0 = blockIdx.y * 32;
    const int tx = threadIdx.x, ty = threadIdx.y;
#pragma unroll
    for (int i = 0; i < 4; ++i) {
        int r = ty + 8 * i;
        tile[r][tx] = vp[(size_t)(t0 + r) * (3 * Cdim) + d0 + tx];
    }
    __syncthreads();
#pragma unroll
    for (int i = 0; i < 4; ++i) {
        int d = ty + 8 * i;
        op[(size_t)(d0 + d) * Tdim + t0 + tx] = tile[tx][d];
    }
}

// ---------- bf16 MFMA GEMM: C = A(M x Kfull) * Bt(N x Kfull)^T, fp32 accum ----
// Double-buffered prefetch, 1 barrier/K-step. Split-K over blockIdx.z:
// kz=0 applies bias/relu/residual and writes outF/outB; kz=1..3 write raw fp32
// partials to outP1/2/3 (consumer sums). Natural block order (swizzle reverted:
// r5 regression suspect; HW block->XCD mapping is undefined).
template<bool BIAS, bool RELU, bool RESID, bool OUTF>
__global__ __launch_bounds__(256) void gemm_k(const uint16_t* __restrict__ A,
                                              const uint16_t* __restrict__ Bt,
                                              int Kfull, int Kp,
                                              float* outF,              // no restrict: may alias resid
                                              uint16_t* __restrict__ outB,
                                              const float* __restrict__ bias,
                                              const float* resid,       // no restrict: may alias outF
                                              float* __restrict__ outP1,
                                              float* __restrict__ outP2,
                                              float* __restrict__ outP3,
                                              int N) {
    __shared__ uint16_t As[2][128 * 32];
    __shared__ uint16_t Bs[2][128 * 32];
    const int bx = blockIdx.x, by = blockIdx.y, kz = blockIdx.z;

    const int tid = threadIdx.x;
    const int wave = tid >> 6, lane = tid & 63;
    const int lg = lane >> 4, lr = lane & 15;
    const int wm = (wave >> 1) << 6, wn = (wave & 1) << 6;
    const uint16_t* ag = A + (size_t)bx * 128 * Kfull + (size_t)(tid >> 2) * Kfull + (tid & 3) * 8 + (size_t)kz * Kp;
    const uint16_t* bg = Bt + (size_t)by * 128 * Kfull + (size_t)(tid >> 2) * Kfull + (tid & 3) * 8 + (size_t)kz * Kp;
    const size_t rstep = (size_t)64 * Kfull;
    const int db0 = wave * 512, db1 = 2048 + wave * 512;   // wave-uniform LDS offsets

    f32x4 acc[4][4];
#pragma unroll
    for (int i = 0; i < 4; ++i)
#pragma unroll
        for (int j = 0; j < 4; ++j) acc[i][j] = (f32x4){0.f, 0.f, 0.f, 0.f};

#define GSTAGE(bi, kk)                                     \
    do {                                                   \
        gload_lds16(ag + (kk), &As[bi][db0]);              \
        gload_lds16(ag + (kk) + rstep, &As[bi][db1]);      \
        gload_lds16(bg + (kk), &Bs[bi][db0]);              \
        gload_lds16(bg + (kk) + rstep, &Bs[bi][db1]);      \
    } while (0)

    GSTAGE(0, 0);
    __syncthreads();
    int cur = 0;
    for (int k0 = 0; k0 < Kp; k0 += 32) {
        if (k0 + 32 < Kp) GSTAGE(cur ^ 1, k0 + 32);
        short8 af[4], bfr[4];
#pragma unroll
        for (int m = 0; m < 4; ++m) af[m] = *(const short8*)(&As[cur][0] + (wm + 16 * m + lr) * 32 + 8 * lg);
#pragma unroll
        for (int n = 0; n < 4; ++n) bfr[n] = *(const short8*)(&Bs[cur][0] + (wn + 16 * n + lr) * 32 + 8 * lg);
#pragma unroll
        for (int m = 0; m < 4; ++m)
#pragma unroll
            for (int n = 0; n < 4; ++n)
                acc[m][n] = __builtin_amdgcn_mfma_f32_16x16x32_bf16(af[m], bfr[n], acc[m][n], 0, 0, 0);
        __syncthreads();
        cur ^= 1;
    }
#undef GSTAGE
    // epilogue: C/D layout col=lane&15, row=4*(lane>>4)+reg  [verified m89/m91]
    if (kz == 0) {
#pragma unroll
        for (int n = 0; n < 4; ++n) {
            const int col = (by << 7) + wn + 16 * n + lr;
            const float bv = BIAS ? bias[col] : 0.f;
#pragma unroll
            for (int m = 0; m < 4; ++m) {
#pragma unroll
                for (int r = 0; r < 4; ++r) {
                    const int row = (bx << 7) + wm + 16 * m + 4 * lg + r;
                    float v = acc[m][n][r] + bv;
                    if (RELU) v = fmaxf(v, 0.f);
                    if (RESID) v += resid[(size_t)row * N + col];
                    if (OUTF) outF[(size_t)row * N + col] = v;
                    else      outB[(size_t)row * N + col] = f2bf(v);
                }
            }
        }
    } else {
        float* op = (kz == 1) ? outP1 : (kz == 2) ? outP2 : outP3;
#pragma unroll
        for (int n = 0; n < 4; ++n) {
            const int col = (by << 7) + wn + 16 * n + lr;
#pragma unroll
            for (int m = 0; m < 4; ++m) {
#pragma unroll
                for (int r = 0; r < 4; ++r) {
                    const int row = (bx << 7) + wm + 16 * m + 4 * lg + r;
                    op[(size_t)row * N + col] = acc[m][n][r];
                }
            }
        }
    }
}

// ---------- flash attention, 4-wave blocks, LDS-staged K/V, balanced pairing ----
__global__ __launch_bounds__(256) void attn_k(const uint16_t* __restrict__ qkv,
                                              const uint16_t* __restrict__ vT,
                                              uint16_t* __restrict__ o) {
    __shared__ uint16_t Kb[2][64 * 64];
    __shared__ uint16_t Vb[2][64 * 64];
    const int tid = threadIdx.x;
    const int wave = tid >> 6, lane = tid & 63;
    const int lg = lane >> 4, lr = lane & 15;
    const int bh = blockIdx.y, b = bh >> 4, h = bh & 15;
    const size_t rs = 3 * Cdim;
    const uint16_t* qp = qkv + (size_t)b * Tdim * rs + (size_t)h * HDdim;
    const uint16_t* kp = qp + Cdim;
    const uint16_t* vtp = vT + (size_t)bh * HDdim * Tdim;

    const int s0 = tid, s1 = tid + 256;
    const int r0v = s0 >> 3, c0v = ((s0 & 7) ^ (r0v & 7)) << 3;
    const int r1v = s1 >> 3, c1v = ((s1 & 7) ^ (r1v & 7)) << 3;
    const int db0 = wave * 512, db1 = 2048 + wave * 512;

#define STAGE(bufi, kvb)                                                        \
    do {                                                                        \
        gload_lds16(kp + (size_t)((kvb) + r0v) * rs + c0v, &Kb[bufi][db0]);     \
        gload_lds16(kp + (size_t)((kvb) + r1v) * rs + c1v, &Kb[bufi][db1]);     \
        gload_lds16(vtp + (size_t)r0v * Tdim + (kvb) + c0v, &Vb[bufi][db0]);    \
        gload_lds16(vtp + (size_t)r1v * Tdim + (kvb) + c1v, &Vb[bufi][db1]);    \
    } while (0)

    const int tiles[2] = {(int)blockIdx.x, 31 - (int)blockIdx.x};

    for (int ti = 0; ti < 2; ++ti) {
        const int tx = tiles[ti];
        const int q0 = tx << 6;
        const int nch = tx + 1;
        const int qrow = q0 + 16 * wave + lr;

        short8 qf[2];
#pragma unroll
        for (int c = 0; c < 2; ++c) {
            short8 raw = *(const short8*)(qp + (size_t)qrow * rs + 32 * c + 8 * lg);
#pragma unroll
            for (int j = 0; j < 8; ++j)
                qf[c][j] = (short)f2bf(bf2f((uint16_t)raw[j]) * 0.125f);
        }

        float m_run = -__builtin_inff(), l_run = 0.f;
        f32x4 oacc[4];
#pragma unroll
        for (int t = 0; t < 4; ++t) oacc[t] = (f32x4){0.f, 0.f, 0.f, 0.f};

        STAGE(0, 0);
        __syncthreads();
        int cur = 0;
        for (int ch = 0; ch < nch; ++ch) {
            if (ch + 1 < nch) STAGE(cur ^ 1, 64 * (ch + 1));
            const int kvb = 64 * ch;
            const char* Kc = (const char*)&Kb[cur][0];
            const char* Vc = (const char*)&Vb[cur][0];
            short8 kf[4][2];
#pragma unroll
            for (int u = 0; u < 4; ++u)
#pragma unroll
                for (int c = 0; c < 2; ++c)
                    kf[u][c] = *(const short8*)(Kc + (16 * u + lr) * 128 +
                                                (((lg + 4 * c) ^ (lr & 7)) << 4));
            f32x4 s4[4];
            __builtin_amdgcn_s_setprio(1);
#pragma unroll
            for (int u = 0; u < 4; ++u) {
                f32x4 z = (f32x4){0.f, 0.f, 0.f, 0.f};
                z = __builtin_amdgcn_mfma_f32_16x16x32_bf16(kf[u][0], qf[0], z, 0, 0, 0);
                z = __builtin_amdgcn_mfma_f32_16x16x32_bf16(kf[u][1], qf[1], z, 0, 0, 0);
                s4[u] = z;
            }
            __builtin_amdgcn_s_setprio(0);
            float p[4][4];
            float mx = -__builtin_inff();
#pragma unroll
            for (int u = 0; u < 4; ++u)
#pragma unroll
                for (int r = 0; r < 4; ++r) {
                    int kv = kvb + 16 * u + 4 * lg + r;
                    float sv = (kv <= qrow) ? s4[u][r] : -__builtin_inff();
                    p[u][r] = sv;
                    mx = fmaxf(mx, sv);
                }
            mx = fmaxf(mx, __shfl_xor(mx, 16));
            mx = fmaxf(mx, __shfl_xor(mx, 32));
            const float m_new = fmaxf(m_run, mx);
            const float alpha = __expf(m_run - m_new);
            float ps = 0.f;
#pragma unroll
            for (int u = 0; u < 4; ++u)
#pragma unroll
                for (int r = 0; r < 4; ++r) {
                    float e = __expf(p[u][r] - m_new);
                    p[u][r] = e; ps += e;
                }
            ps += __shfl_xor(ps, 16);
            ps += __shfl_xor(ps, 32);
            l_run = l_run * alpha + ps;
            m_run = m_new;
            short8 pb[2];
#pragma unroll
            for (int hh = 0; hh < 2; ++hh)
#pragma unroll
                for (int j = 0; j < 4; ++j) {
                    pb[hh][j]     = (short)f2bf(p[2 * hh][j]);
                    pb[hh][j + 4] = (short)f2bf(p[2 * hh + 1][j]);
                }
            __builtin_amdgcn_s_setprio(1);
#pragma unroll
            for (int t = 0; t < 4; ++t) {
                f32x4 oa = oacc[t];
#pragma unroll
                for (int r = 0; r < 4; ++r) oa[r] *= alpha;
                const int vbase = (16 * t + lr) * 128;
                const int sw = (lr & 7) << 4;
#pragma unroll
                for (int hh = 0; hh < 2; ++hh) {
                    short4v v0 = *(const short4v*)(Vc + vbase + ((64 * hh + 8 * lg) ^ sw));
                    short4v v1 = *(const short4v*)(Vc + vbase + ((64 * hh + 32 + 8 * lg) ^ sw));
                    short8 vf = (short8){v0[0], v0[1], v0[2], v0[3], v1[0], v1[1], v1[2], v1[3]};
                    oa = __builtin_amdgcn_mfma_f32_16x16x32_bf16(vf, pb[hh], oa, 0, 0, 0);
                }
                oacc[t] = oa;
            }
            __builtin_amdgcn_s_setprio(0);
            __syncthreads();
            cur ^= 1;
        }
        const float inv = 1.f / l_run;
        uint16_t* orow = o + (size_t)(b * Tdim + qrow) * Cdim + h * HDdim;
#pragma unroll
        for (int t = 0; t < 4; ++t)
#pragma unroll
            for (int r = 0; r < 4; ++r)
                orow[16 * t + 4 * lg + r] = f2bf(oacc[t][r] * inv);
        __syncthreads();
    }
#undef STAGE
}

// ---------- LayerNorm over rows of 1024: in (+ up to 3 partials) summed ----------
__global__ __launch_bounds__(256) void ln_k(const float* __restrict__ in,
                                            const float* __restrict__ in2,
                                            const float* __restrict__ in3,
                                            const float* __restrict__ in4,
                                            const float* __restrict__ g,
                                            const float* __restrict__ be,
                                            float* __restrict__ outF,
                                            uint16_t* __restrict__ outB) {
    const int row = blockIdx.x, tid = threadIdx.x;
    const size_t base = (size_t)row * Cdim + tid * 4;
    f32x4 xv = *(const f32x4*)(in + base);
    if (in2) {
        f32x4 yv = *(const f32x4*)(in2 + base);
#pragma unroll
        for (int j = 0; j < 4; ++j) xv[j] += yv[j];
    }
    if (in3) {
        f32x4 yv = *(const f32x4*)(in3 + base);
#pragma unroll
        for (int j = 0; j < 4; ++j) xv[j] += yv[j];
    }
    if (in4) {
        f32x4 yv = *(const f32x4*)(in4 + base);
#pragma unroll
        for (int j = 0; j < 4; ++j) xv[j] += yv[j];
    }
    float s = xv[0] + xv[1] + xv[2] + xv[3];
    float q = xv[0] * xv[0] + xv[1] * xv[1] + xv[2] * xv[2] + xv[3] * xv[3];
#pragma unroll
    for (int off = 1; off < 64; off <<= 1) { s += __shfl_xor(s, off); q += __shfl_xor(q, off); }
    __shared__ float sm[4], sq[4];
    if ((tid & 63) == 0) { sm[tid >> 6] = s; sq[tid >> 6] = q; }
    __syncthreads();
    s = sm[0] + sm[1] + sm[2] + sm[3];
    q = sq[0] + sq[1] + sq[2] + sq[3];
    const float mu = s * (1.f / 1024.f);
    const float var = q * (1.f / 1024.f) - mu * mu;
    const float rstd = rsqrtf(var + 1e-5f);
#pragma unroll
    for (int j = 0; j < 4; ++j) {
        int col = tid * 4 + j;
        float y = (xv[j] - mu) * rstd * g[col] + be[col];
        if (outF) outF[(size_t)row * Cdim + col] = y;
        if (outB) outB[(size_t)row * Cdim + col] = f2bf(y);
    }
}

// ---------- launch ----------
extern "C" void kernel_launch(void* const* d_in, const int* in_sizes, int n_in,
                              void* d_out, int out_size, void* d_ws, size_t ws_size,
                              hipStream_t stream) {
    const float* x   = (const float*)d_in[0];
    const float* Wq  = (const float*)d_in[1];
    const float* Wk  = (const float*)d_in[2];
    const float* Wv  = (const float*)d_in[3];
    const float* Wp  = (const float*)d_in[4];
    const float* bp  = (const float*)d_in[5];
    const float* W1  = (const float*)d_in[6];
    const float* b1  = (const float*)d_in[7];
    const float* W2  = (const float*)d_in[8];
    const float* b2  = (const float*)d_in[9];
    const float* g1  = (const float*)d_in[10];
    const float* be1 = (const float*)d_in[11];
    const float* g2  = (const float*)d_in[12];
    const float* be2 = (const float*)d_in[13];
    float* out = (float*)d_out;

    // workspace layout (112 MB), live-range aliased:
    //  [  0, 24M) qkv (2-4) | P1p proj partial (5-6) | h1 [0,32M) (7-8)
    //  [ 24, 32M) obuf (4-5) | (h1 tail)
    //  [ 32, 40M) xb (1-2) | vT (3-4) | x1b (6-7)   | Q2 [32,48M) (8-9)
    //  [ 40, 46M) wqkv (1-2)                        | (Q2 tail)
    //  [ 46, 48M) wpt (1-5)                         | (Q2 tail)
    //  [ 48, 64M) resid = proj out (5-6) | Q1 (8-9)
    //  [ 64, 80M) x1f (6-8), FFN2 kz0 RMW in place (8), LN2 reads (9)
    //  [ 80, 88M) w1t (1-7)
    //  [ 88, 96M) w2t (1-8)
    //  [ 96,112M) Q3 (8-9)
    char* ws = (char*)d_ws;
    uint16_t* qkv   = (uint16_t*)(ws + 0);
    float*    P1p   = (float*)   (ws + 0);
    uint16_t* h1    = (uint16_t*)(ws + 0);
    uint16_t* obuf  = (uint16_t*)(ws + 25165824);
    uint16_t* xb    = (uint16_t*)(ws + 33554432);
    uint16_t* vT    = (uint16_t*)(ws + 33554432);
    uint16_t* x1b   = (uint16_t*)(ws + 33554432);
    float*    Q2    = (float*)   (ws + 33554432);
    uint16_t* wqkv  = (uint16_t*)(ws + 41943040);
    uint16_t* wpt   = (uint16_t*)(ws + 48234496);
    float*    resid = (float*)   (ws + 50331648);
    float*    Q1    = (float*)   (ws + 50331648);
    float*    x1f   = (float*)   (ws + 67108864);
    uint16_t* w1t   = (uint16_t*)(ws + 83886080);
    uint16_t* w2t   = (uint16_t*)(ws + 92274688);
    float*    Q3    = (float*)   (ws + 100663296);

    // step 1: pack / cast
    cast4_k<<<4096, 256, 0, stream>>>(x, xb);
    transpose_tile<<<dim3(32, 2, 16), dim3(32, 8), 0, stream>>>(Wq, wqkv,           1024, 64, 65536, 65536);
    transpose_tile<<<dim3(32, 2, 16), dim3(32, 8), 0, stream>>>(Wk, wqkv + 1048576, 1024, 64, 65536, 65536);
    transpose_tile<<<dim3(32, 2, 16), dim3(32, 8), 0, stream>>>(Wv, wqkv + 2097152, 1024, 64, 65536, 65536);
    transpose_tile<<<dim3(32, 32, 1),  dim3(32, 8), 0, stream>>>(Wp, wpt, 1024, 1024, 0, 0);
    transpose_tile<<<dim3(32, 128, 1), dim3(32, 8), 0, stream>>>(W1, w1t, 1024, 4096, 0, 0);
    transpose_tile<<<dim3(128, 32, 1), dim3(32, 8), 0, stream>>>(W2, w2t, 4096, 1024, 0, 0);

    // step 2: QKV projection (768 blocks = 3/CU)
    gemm_k<false, false, false, false><<<dim3(32, 24, 1), 256, 0, stream>>>(
        xb, wqkv, Cdim, Cdim, nullptr, qkv, nullptr, nullptr,
        nullptr, nullptr, nullptr, 3 * Cdim);
    // step 3: V^T pack
    vtrans_k<<<dim3(64, 2, 32), dim3(32, 8), 0, stream>>>(qkv, vT);
    // step 4: attention
    attn_k<<<dim3(16, 32), 256, 0, stream>>>(qkv, vT, obuf);
    // step 5: output projection, split-K=2 (512 blocks = 2/CU):
    //   kz=0 -> resid = partial + bp + x ; kz=1 -> P1p raw partial
    gemm_k<true, false, true, true><<<dim3(32, 8, 2), 256, 0, stream>>>(
        obuf, wpt, Cdim, Cdim / 2, resid, nullptr, bp, x,
        P1p, nullptr, nullptr, Cdim);
    // step 6: LN1 over (resid + P1p) -> x1f (fp32) + x1b (bf16)
    ln_k<<<Mdim, 256, 0, stream>>>(resid, P1p, nullptr, nullptr, g1, be1, x1f, x1b);
    // step 7: FFN1 relu(x1 @ W1 + b1) -> h1 (1024 blocks = 4/CU)
    gemm_k<true, true, false, false><<<dim3(32, 32, 1), 256, 0, stream>>>(
        x1b, w1t, Cdim, Cdim, nullptr, h1, b1, nullptr,
        nullptr, nullptr, nullptr, FFdim);
    // step 8: FFN2, split-K=4 (1024 blocks = 4/CU):
    //   kz=0 -> x1f += partial + b2 (in-place, per-thread exclusive RMW)
    //   kz=1..3 -> Q1/Q2/Q3 raw fp32 partials
    gemm_k<true, false, true, true><<<dim3(32, 8, 4), 256, 0, stream>>>(
        h1, w2t, FFdim, FFdim / 4, x1f, nullptr, b2, x1f,
        Q1, Q2, Q3, Cdim);
    // step 9: LN2 over (x1f + Q1 + Q2 + Q3) -> out
    ln_k<<<Mdim, 256, 0, stream>>>(x1f, Q1, Q2, Q3, g2, be2, out, nullptr);
}

// Round 7
// 298.631 us; speedup vs baseline: 1.1113x; 1.0420x over previous
//
#include <hip/hip_runtime.h>
#include <cstdint>
#include <cstddef>

// ---------- types ----------
typedef __attribute__((ext_vector_type(8))) short short8;
typedef __attribute__((ext_vector_type(4))) short short4v;
typedef __attribute__((ext_vector_type(4))) float f32x4;

#define Bdim 2
#define Tdim 2048
#define Cdim 1024
#define Hdim 16
#define HDdim 64
#define Mdim (Bdim*Tdim)   // 4096
#define FFdim (4*Cdim)     // 4096

__device__ __forceinline__ uint16_t f2bf(float f) {
    union { float f; uint32_t u; } v; v.f = f;
    uint32_t x = v.u;
    uint32_t r = x + 0x7FFFu + ((x >> 16) & 1u);
    return (uint16_t)(r >> 16);
}
__device__ __forceinline__ float bf2f(uint16_t h) {
    union { float f; uint32_t u; } v; v.u = ((uint32_t)h) << 16; return v.f;
}

// async global->LDS, 16B per lane. dst must be wave-uniform base; HW adds lane*16.
__device__ __forceinline__ void gload_lds16(const uint16_t* g, uint16_t* l) {
    __builtin_amdgcn_global_load_lds(
        (const __attribute__((address_space(1))) void*)g,
        (__attribute__((address_space(3))) void*)l, 16, 0, 0);
}

#define RAW_BAR()   asm volatile("s_barrier" ::: "memory")
#define VMCNT(N)    asm volatile("s_waitcnt vmcnt(" #N ")" ::: "memory")

// ---------- elementwise cast f32 -> bf16 (vectorized x4) ----------
__global__ __launch_bounds__(256) void cast4_k(const float* __restrict__ in,
                                               uint16_t* __restrict__ out) {
    int i = (blockIdx.x * 256 + threadIdx.x) * 4;
    f32x4 v = *(const f32x4*)(in + i);
    short4v o;
#pragma unroll
    for (int j = 0; j < 4; ++j) o[j] = (short)f2bf(v[j]);
    *(short4v*)(out + i) = o;
}

// ---------- tiled transpose f32(R x Cc) -> bf16(Cc x R), batched ----------
__global__ __launch_bounds__(256) void transpose_tile(const float* __restrict__ in,
                                                      uint16_t* __restrict__ out,
                                                      int R, int Cc,
                                                      size_t ibs, size_t obs) {
    __shared__ uint16_t tile[32][33];
    const float* ip = in + (size_t)blockIdx.z * ibs;
    uint16_t* op = out + (size_t)blockIdx.z * obs;
    int r0 = blockIdx.x * 32, n0 = blockIdx.y * 32;
    int tx = threadIdx.x, ty = threadIdx.y;
#pragma unroll
    for (int i = 0; i < 4; ++i) {
        int r = ty + 8 * i;
        tile[r][tx] = f2bf(ip[(size_t)(r0 + r) * Cc + n0 + tx]);
    }
    __syncthreads();
#pragma unroll
    for (int i = 0; i < 4; ++i) {
        int n = ty + 8 * i;
        op[(size_t)(n0 + n) * R + r0 + tx] = tile[tx][n];
    }
}

// ---------- per-head V transpose: qkv V slice -> vT[bh][d=64][t=T] bf16 ----------
__global__ __launch_bounds__(256) void vtrans_k(const uint16_t* __restrict__ qkv,
                                                uint16_t* __restrict__ vT) {
    __shared__ uint16_t tile[32][33];
    const int bh = blockIdx.z, b = bh >> 4, h = bh & 15;
    const uint16_t* vp = qkv + (size_t)b * Tdim * (3 * Cdim) + 2 * Cdim + h * HDdim;
    uint16_t* op = vT + (size_t)bh * HDdim * Tdim;
    const int t0 = blockIdx.x * 32, d0 = blockIdx.y * 32;
    const int tx = threadIdx.x, ty = threadIdx.y;
#pragma unroll
    for (int i = 0; i < 4; ++i) {
        int r = ty + 8 * i;
        tile[r][tx] = vp[(size_t)(t0 + r) * (3 * Cdim) + d0 + tx];
    }
    __syncthreads();
#pragma unroll
    for (int i = 0; i < 4; ++i) {
        int d = ty + 8 * i;
        op[(size_t)(d0 + d) * Tdim + t0 + tx] = tile[tx][d];
    }
}

// ================= 256x256 8-phase GEMM (T2+T3+T4+T5) =================
// C = A(M x Kfull) * Bt(N x Kfull)^T. 512 thr = 8 waves (2M x 4N), BK=64,
// LDS 128KB = 2 dbuf x {A,B} x 2 half x 128 x 64 bf16, XOR-swizzled (g^=row&7)
// on BOTH stage-source and ds_read (rule 21). Counted vmcnt: tile t+1 staged
// during tile t-1 (B halves in phase 2, A halves in phase 3 -- safe because
// B(p)/A(p) LDS reads are barrier-drained by then); boundary waits vmcnt(8)
// (= t+2's loads outstanding), never 0 in steady state.
template<bool BIAS, bool RELU, bool RESID, bool OUTF>
__global__ __launch_bounds__(512, 2) void gemm8_k(const uint16_t* __restrict__ A,
                                                  const uint16_t* __restrict__ Bt,
                                                  int Kfull, int Kp,
                                                  float* outF,              // may alias resid
                                                  uint16_t* __restrict__ outB,
                                                  const float* __restrict__ bias,
                                                  const float* resid,       // may alias outF
                                                  float* __restrict__ outP1,
                                                  float* __restrict__ outP2,
                                                  float* __restrict__ outP3,
                                                  int N) {
    __shared__ uint16_t lds8[65536];   // 128 KiB
    const int bx = blockIdx.x, by = blockIdx.y, kz = blockIdx.z;
    const int tid = threadIdx.x;
    const int wave = tid >> 6, lane = tid & 63;
    const int lg = lane >> 4, lr = lane & 15, lr7 = lr & 7;
    const int wm = wave >> 2, wn = wave & 3;      // 2 x 4 wave grid
    const int NT = Kp >> 6;                        // K-tiles of 64

    // ---- ds_read addressing (element units; 8 el = 16B group) ----
    const int aC = wm * 8192 + lr * 64;                                  // + p*16384
    const int bC = 32768 + (wn >> 1) * 8192 + (wn & 1) * 4096 + lr * 64; // + p*16384
    const int g0 = 8 * (lg ^ lr7);
    const int g1 = 8 * ((4 + lg) ^ lr7);

    // ---- stage addressing: thread covers LDS slot s=tid (and s=tid+512) ----
    const int srow = tid >> 3;                        // 0..63 (issue2: +64)
    const int scol = 8 * ((tid & 7) ^ (srow & 7));    // pre-swizzled source col
    const uint16_t* aSrc = A + (size_t)(bx * 256 + srow) * Kfull + (size_t)kz * Kp + scol;
    const uint16_t* bSrc = Bt + (size_t)(by * 256 + srow) * Kfull + (size_t)kz * Kp + scol;
    const size_t r64 = (size_t)64 * Kfull, r128 = (size_t)128 * Kfull;

#define STG_A(pp, h, tt) do {                                                     \
        const uint16_t* s_ = aSrc + (h) * r128 + (size_t)(tt) * 64;               \
        uint16_t* d_ = &lds8[(pp) * 16384 + (h) * 8192 + wave * 512];             \
        gload_lds16(s_, d_); gload_lds16(s_ + r64, d_ + 4096);                    \
    } while (0)
#define STG_B(pp, h, tt) do {                                                     \
        const uint16_t* s_ = bSrc + (h) * r128 + (size_t)(tt) * 64;               \
        uint16_t* d_ = &lds8[32768 + (pp) * 16384 + (h) * 8192 + wave * 512];     \
        gload_lds16(s_, d_); gload_lds16(s_ + r64, d_ + 4096);                    \
    } while (0)
#define LD8(off) (*(const short8*)&lds8[off])
#define MM(M, Nn, AF, BF) acc[M][Nn] = __builtin_amdgcn_mfma_f32_16x16x32_bf16(AF, BF, acc[M][Nn], 0, 0, 0)

    f32x4 acc[8][4];
#pragma unroll
    for (int i = 0; i < 8; ++i)
#pragma unroll
        for (int j = 0; j < 4; ++j) acc[i][j] = (f32x4){0.f, 0.f, 0.f, 0.f};

    // ---- prologue: stage tile 0 (buf0) and tile 1 (buf1) ----
    STG_B(0, 0, 0); STG_B(0, 1, 0); STG_A(0, 0, 0); STG_A(0, 1, 0);
    if (NT > 1) { STG_B(1, 0, 1); STG_B(1, 1, 1); STG_A(1, 0, 1); STG_A(1, 1, 1); VMCNT(8); }
    else VMCNT(0);
    RAW_BAR();

    short8 af[4][2], bf0[2][2], bf1[2][2];
    for (int t = 0; t < NT; ++t) {
        const int p = t & 1, p16 = p << 14;
        const bool nx1 = (t + 1 < NT), nx2 = (t + 2 < NT);
        // ---- phase 0: read A m0-3 + B n0-1; MFMA quadrant (m0-3, n0-1) ----
#pragma unroll
        for (int m = 0; m < 4; ++m) {
            af[m][0] = LD8(p16 + aC + 1024 * m + g0);
            af[m][1] = LD8(p16 + aC + 1024 * m + g1);
        }
#pragma unroll
        for (int n = 0; n < 2; ++n) {
            bf0[n][0] = LD8(p16 + bC + 1024 * n + g0);
            bf0[n][1] = LD8(p16 + bC + 1024 * n + g1);
        }
        RAW_BAR();
        __builtin_amdgcn_s_setprio(1);
#pragma unroll
        for (int m = 0; m < 4; ++m)
#pragma unroll
            for (int n = 0; n < 2; ++n) { MM(m, n, af[m][0], bf0[n][0]); MM(m, n, af[m][1], bf0[n][1]); }
        __builtin_amdgcn_s_setprio(0);
        RAW_BAR();
        // ---- phase 1: read B n2-3; MFMA (m0-3, n2-3) ----
#pragma unroll
        for (int n = 0; n < 2; ++n) {
            bf1[n][0] = LD8(p16 + bC + 1024 * (n + 2) + g0);
            bf1[n][1] = LD8(p16 + bC + 1024 * (n + 2) + g1);
        }
        RAW_BAR();
        __builtin_amdgcn_s_setprio(1);
#pragma unroll
        for (int m = 0; m < 4; ++m)
#pragma unroll
            for (int n = 0; n < 2; ++n) { MM(m, n + 2, af[m][0], bf1[n][0]); MM(m, n + 2, af[m][1], bf1[n][1]); }
        __builtin_amdgcn_s_setprio(0);
        RAW_BAR();
        // ---- phase 2: read A m4-7 (B(p) LDS now dead); stage t+2 B -> buf p ----
#pragma unroll
        for (int m = 0; m < 4; ++m) {
            af[m][0] = LD8(p16 + aC + 1024 * (m + 4) + g0);
            af[m][1] = LD8(p16 + aC + 1024 * (m + 4) + g1);
        }
        if (nx2) { STG_B(p, 0, t + 2); STG_B(p, 1, t + 2); }
        RAW_BAR();
        __builtin_amdgcn_s_setprio(1);
#pragma unroll
        for (int m = 0; m < 4; ++m)
#pragma unroll
            for (int n = 0; n < 2; ++n) { MM(m + 4, n + 2, af[m][0], bf1[n][0]); MM(m + 4, n + 2, af[m][1], bf1[n][1]); }
        __builtin_amdgcn_s_setprio(0);
        RAW_BAR();
        // ---- phase 3: stage t+2 A -> buf p (A(p) LDS dead); MFMA (m4-7, n0-1) ----
        if (nx2) { STG_A(p, 0, t + 2); STG_A(p, 1, t + 2); }
        RAW_BAR();
        __builtin_amdgcn_s_setprio(1);
#pragma unroll
        for (int m = 0; m < 4; ++m)
#pragma unroll
            for (int n = 0; n < 2; ++n) { MM(m + 4, n, af[m][0], bf0[n][0]); MM(m + 4, n, af[m][1], bf0[n][1]); }
        __builtin_amdgcn_s_setprio(0);
        // ---- boundary: next tile's data must be landed; keep t+2 in flight ----
        if (nx1) {
            if (nx2) VMCNT(8); else VMCNT(0);
            RAW_BAR();
        }
    }
#undef STG_A
#undef STG_B
#undef LD8
#undef MM
    // ---- epilogue: C/D layout col=lane&15, row=4*(lane>>4)+reg ----
    if (kz == 0) {
#pragma unroll
        for (int n = 0; n < 4; ++n) {
            const int col = (by << 8) + wn * 64 + 16 * n + lr;
            const float bv = BIAS ? bias[col] : 0.f;
#pragma unroll
            for (int m = 0; m < 8; ++m) {
#pragma unroll
                for (int r = 0; r < 4; ++r) {
                    const int row = (bx << 8) + wm * 128 + 16 * m + 4 * lg + r;
                    float v = acc[m][n][r] + bv;
                    if (RELU) v = fmaxf(v, 0.f);
                    if (RESID) v += resid[(size_t)row * N + col];
                    if (OUTF) outF[(size_t)row * N + col] = v;
                    else      outB[(size_t)row * N + col] = f2bf(v);
                }
            }
        }
    } else {
        float* op = (kz == 1) ? outP1 : (kz == 2) ? outP2 : outP3;
#pragma unroll
        for (int n = 0; n < 4; ++n) {
            const int col = (by << 8) + wn * 64 + 16 * n + lr;
#pragma unroll
            for (int m = 0; m < 8; ++m) {
#pragma unroll
                for (int r = 0; r < 4; ++r) {
                    const int row = (bx << 8) + wm * 128 + 16 * m + 4 * lg + r;
                    op[(size_t)row * N + col] = acc[m][n][r];
                }
            }
        }
    }
}

// ---------- 128^2 2-phase GEMM (kept for proj: NT too short for 8-phase) ----
template<bool BIAS, bool RELU, bool RESID, bool OUTF>
__global__ __launch_bounds__(256) void gemm_k(const uint16_t* __restrict__ A,
                                              const uint16_t* __restrict__ Bt,
                                              int Kfull, int Kp,
                                              float* outF,
                                              uint16_t* __restrict__ outB,
                                              const float* __restrict__ bias,
                                              const float* resid,
                                              float* __restrict__ outP1,
                                              int N) {
    __shared__ uint16_t As[2][128 * 32];
    __shared__ uint16_t Bs[2][128 * 32];
    const int bx = blockIdx.x, by = blockIdx.y, kz = blockIdx.z;
    const int tid = threadIdx.x;
    const int wave = tid >> 6, lane = tid & 63;
    const int lg = lane >> 4, lr = lane & 15;
    const int wm = (wave >> 1) << 6, wn = (wave & 1) << 6;
    const uint16_t* ag = A + (size_t)bx * 128 * Kfull + (size_t)(tid >> 2) * Kfull + (tid & 3) * 8 + (size_t)kz * Kp;
    const uint16_t* bg = Bt + (size_t)by * 128 * Kfull + (size_t)(tid >> 2) * Kfull + (tid & 3) * 8 + (size_t)kz * Kp;
    const size_t rstep = (size_t)64 * Kfull;
    const int db0 = wave * 512, db1 = 2048 + wave * 512;

    f32x4 acc[4][4];
#pragma unroll
    for (int i = 0; i < 4; ++i)
#pragma unroll
        for (int j = 0; j < 4; ++j) acc[i][j] = (f32x4){0.f, 0.f, 0.f, 0.f};

#define GSTAGE(bi, kk)                                     \
    do {                                                   \
        gload_lds16(ag + (kk), &As[bi][db0]);              \
        gload_lds16(ag + (kk) + rstep, &As[bi][db1]);      \
        gload_lds16(bg + (kk), &Bs[bi][db0]);              \
        gload_lds16(bg + (kk) + rstep, &Bs[bi][db1]);      \
    } while (0)

    GSTAGE(0, 0);
    __syncthreads();
    int cur = 0;
    for (int k0 = 0; k0 < Kp; k0 += 32) {
        if (k0 + 32 < Kp) GSTAGE(cur ^ 1, k0 + 32);
        short8 af[4], bfr[4];
#pragma unroll
        for (int m = 0; m < 4; ++m) af[m] = *(const short8*)(&As[cur][0] + (wm + 16 * m + lr) * 32 + 8 * lg);
#pragma unroll
        for (int n = 0; n < 4; ++n) bfr[n] = *(const short8*)(&Bs[cur][0] + (wn + 16 * n + lr) * 32 + 8 * lg);
#pragma unroll
        for (int m = 0; m < 4; ++m)
#pragma unroll
            for (int n = 0; n < 4; ++n)
                acc[m][n] = __builtin_amdgcn_mfma_f32_16x16x32_bf16(af[m], bfr[n], acc[m][n], 0, 0, 0);
        __syncthreads();
        cur ^= 1;
    }
#undef GSTAGE
    if (kz == 0) {
#pragma unroll
        for (int n = 0; n < 4; ++n) {
            const int col = (by << 7) + wn + 16 * n + lr;
            const float bv = BIAS ? bias[col] : 0.f;
#pragma unroll
            for (int m = 0; m < 4; ++m) {
#pragma unroll
                for (int r = 0; r < 4; ++r) {
                    const int row = (bx << 7) + wm + 16 * m + 4 * lg + r;
                    float v = acc[m][n][r] + bv;
                    if (RELU) v = fmaxf(v, 0.f);
                    if (RESID) v += resid[(size_t)row * N + col];
                    if (OUTF) outF[(size_t)row * N + col] = v;
                    else      outB[(size_t)row * N + col] = f2bf(v);
                }
            }
        }
    } else {
#pragma unroll
        for (int n = 0; n < 4; ++n) {
            const int col = (by << 7) + wn + 16 * n + lr;
#pragma unroll
            for (int m = 0; m < 4; ++m) {
#pragma unroll
                for (int r = 0; r < 4; ++r) {
                    const int row = (bx << 7) + wm + 16 * m + 4 * lg + r;
                    outP1[(size_t)row * N + col] = acc[m][n][r];
                }
            }
        }
    }
}

// ---------- flash attention, 4-wave blocks, LDS-staged K/V, balanced pairing ----
__global__ __launch_bounds__(256) void attn_k(const uint16_t* __restrict__ qkv,
                                              const uint16_t* __restrict__ vT,
                                              uint16_t* __restrict__ o) {
    __shared__ uint16_t Kb[2][64 * 64];
    __shared__ uint16_t Vb[2][64 * 64];
    const int tid = threadIdx.x;
    const int wave = tid >> 6, lane = tid & 63;
    const int lg = lane >> 4, lr = lane & 15;
    const int bh = blockIdx.y, b = bh >> 4, h = bh & 15;
    const size_t rs = 3 * Cdim;
    const uint16_t* qp = qkv + (size_t)b * Tdim * rs + (size_t)h * HDdim;
    const uint16_t* kp = qp + Cdim;
    const uint16_t* vtp = vT + (size_t)bh * HDdim * Tdim;

    const int s0 = tid, s1 = tid + 256;
    const int r0v = s0 >> 3, c0v = ((s0 & 7) ^ (r0v & 7)) << 3;
    const int r1v = s1 >> 3, c1v = ((s1 & 7) ^ (r1v & 7)) << 3;
    const int db0 = wave * 512, db1 = 2048 + wave * 512;

#define STAGE(bufi, kvb)                                                        \
    do {                                                                        \
        gload_lds16(kp + (size_t)((kvb) + r0v) * rs + c0v, &Kb[bufi][db0]);     \
        gload_lds16(kp + (size_t)((kvb) + r1v) * rs + c1v, &Kb[bufi][db1]);     \
        gload_lds16(vtp + (size_t)r0v * Tdim + (kvb) + c0v, &Vb[bufi][db0]);    \
        gload_lds16(vtp + (size_t)r1v * Tdim + (kvb) + c1v, &Vb[bufi][db1]);    \
    } while (0)

    const int tiles[2] = {(int)blockIdx.x, 31 - (int)blockIdx.x};

    for (int ti = 0; ti < 2; ++ti) {
        const int tx = tiles[ti];
        const int q0 = tx << 6;
        const int nch = tx + 1;
        const int qrow = q0 + 16 * wave + lr;

        short8 qf[2];
#pragma unroll
        for (int c = 0; c < 2; ++c) {
            short8 raw = *(const short8*)(qp + (size_t)qrow * rs + 32 * c + 8 * lg);
#pragma unroll
            for (int j = 0; j < 8; ++j)
                qf[c][j] = (short)f2bf(bf2f((uint16_t)raw[j]) * 0.125f);
        }

        float m_run = -__builtin_inff(), l_run = 0.f;
        f32x4 oacc[4];
#pragma unroll
        for (int t = 0; t < 4; ++t) oacc[t] = (f32x4){0.f, 0.f, 0.f, 0.f};

        STAGE(0, 0);
        __syncthreads();
        int cur = 0;
        for (int ch = 0; ch < nch; ++ch) {
            if (ch + 1 < nch) STAGE(cur ^ 1, 64 * (ch + 1));
            const int kvb = 64 * ch;
            const char* Kc = (const char*)&Kb[cur][0];
            const char* Vc = (const char*)&Vb[cur][0];
            short8 kf[4][2];
#pragma unroll
            for (int u = 0; u < 4; ++u)
#pragma unroll
                for (int c = 0; c < 2; ++c)
                    kf[u][c] = *(const short8*)(Kc + (16 * u + lr) * 128 +
                                                (((lg + 4 * c) ^ (lr & 7)) << 4));
            f32x4 s4[4];
            __builtin_amdgcn_s_setprio(1);
#pragma unroll
            for (int u = 0; u < 4; ++u) {
                f32x4 z = (f32x4){0.f, 0.f, 0.f, 0.f};
                z = __builtin_amdgcn_mfma_f32_16x16x32_bf16(kf[u][0], qf[0], z, 0, 0, 0);
                z = __builtin_amdgcn_mfma_f32_16x16x32_bf16(kf[u][1], qf[1], z, 0, 0, 0);
                s4[u] = z;
            }
            __builtin_amdgcn_s_setprio(0);
            float p[4][4];
            float mx = -__builtin_inff();
#pragma unroll
            for (int u = 0; u < 4; ++u)
#pragma unroll
                for (int r = 0; r < 4; ++r) {
                    int kv = kvb + 16 * u + 4 * lg + r;
                    float sv = (kv <= qrow) ? s4[u][r] : -__builtin_inff();
                    p[u][r] = sv;
                    mx = fmaxf(mx, sv);
                }
            mx = fmaxf(mx, __shfl_xor(mx, 16));
            mx = fmaxf(mx, __shfl_xor(mx, 32));
            const float m_new = fmaxf(m_run, mx);
            const float alpha = __expf(m_run - m_new);
            float ps = 0.f;
#pragma unroll
            for (int u = 0; u < 4; ++u)
#pragma unroll
                for (int r = 0; r < 4; ++r) {
                    float e = __expf(p[u][r] - m_new);
                    p[u][r] = e; ps += e;
                }
            ps += __shfl_xor(ps, 16);
            ps += __shfl_xor(ps, 32);
            l_run = l_run * alpha + ps;
            m_run = m_new;
            short8 pb[2];
#pragma unroll
            for (int hh = 0; hh < 2; ++hh)
#pragma unroll
                for (int j = 0; j < 4; ++j) {
                    pb[hh][j]     = (short)f2bf(p[2 * hh][j]);
                    pb[hh][j + 4] = (short)f2bf(p[2 * hh + 1][j]);
                }
            __builtin_amdgcn_s_setprio(1);
#pragma unroll
            for (int t = 0; t < 4; ++t) {
                f32x4 oa = oacc[t];
#pragma unroll
                for (int r = 0; r < 4; ++r) oa[r] *= alpha;
                const int vbase = (16 * t + lr) * 128;
                const int sw = (lr & 7) << 4;
#pragma unroll
                for (int hh = 0; hh < 2; ++hh) {
                    short4v v0 = *(const short4v*)(Vc + vbase + ((64 * hh + 8 * lg) ^ sw));
                    short4v v1 = *(const short4v*)(Vc + vbase + ((64 * hh + 32 + 8 * lg) ^ sw));
                    short8 vf = (short8){v0[0], v0[1], v0[2], v0[3], v1[0], v1[1], v1[2], v1[3]};
                    oa = __builtin_amdgcn_mfma_f32_16x16x32_bf16(vf, pb[hh], oa, 0, 0, 0);
                }
                oacc[t] = oa;
            }
            __builtin_amdgcn_s_setprio(0);
            __syncthreads();
            cur ^= 1;
        }
        const float inv = 1.f / l_run;
        uint16_t* orow = o + (size_t)(b * Tdim + qrow) * Cdim + h * HDdim;
#pragma unroll
        for (int t = 0; t < 4; ++t)
#pragma unroll
            for (int r = 0; r < 4; ++r)
                orow[16 * t + 4 * lg + r] = f2bf(oacc[t][r] * inv);
        __syncthreads();
    }
#undef STAGE
}

// ---------- LayerNorm over rows of 1024: in (+ up to 3 partials) summed ----------
__global__ __launch_bounds__(256) void ln_k(const float* __restrict__ in,
                                            const float* __restrict__ in2,
                                            const float* __restrict__ in3,
                                            const float* __restrict__ in4,
                                            const float* __restrict__ g,
                                            const float* __restrict__ be,
                                            float* __restrict__ outF,
                                            uint16_t* __restrict__ outB) {
    const int row = blockIdx.x, tid = threadIdx.x;
    const size_t base = (size_t)row * Cdim + tid * 4;
    f32x4 xv = *(const f32x4*)(in + base);
    if (in2) {
        f32x4 yv = *(const f32x4*)(in2 + base);
#pragma unroll
        for (int j = 0; j < 4; ++j) xv[j] += yv[j];
    }
    if (in3) {
        f32x4 yv = *(const f32x4*)(in3 + base);
#pragma unroll
        for (int j = 0; j < 4; ++j) xv[j] += yv[j];
    }
    if (in4) {
        f32x4 yv = *(const f32x4*)(in4 + base);
#pragma unroll
        for (int j = 0; j < 4; ++j) xv[j] += yv[j];
    }
    float s = xv[0] + xv[1] + xv[2] + xv[3];
    float q = xv[0] * xv[0] + xv[1] * xv[1] + xv[2] * xv[2] + xv[3] * xv[3];
#pragma unroll
    for (int off = 1; off < 64; off <<= 1) { s += __shfl_xor(s, off); q += __shfl_xor(q, off); }
    __shared__ float sm[4], sq[4];
    if ((tid & 63) == 0) { sm[tid >> 6] = s; sq[tid >> 6] = q; }
    __syncthreads();
    s = sm[0] + sm[1] + sm[2] + sm[3];
    q = sq[0] + sq[1] + sq[2] + sq[3];
    const float mu = s * (1.f / 1024.f);
    const float var = q * (1.f / 1024.f) - mu * mu;
    const float rstd = rsqrtf(var + 1e-5f);
#pragma unroll
    for (int j = 0; j < 4; ++j) {
        int col = tid * 4 + j;
        float y = (xv[j] - mu) * rstd * g[col] + be[col];
        if (outF) outF[(size_t)row * Cdim + col] = y;
        if (outB) outB[(size_t)row * Cdim + col] = f2bf(y);
    }
}

// ---------- launch ----------
extern "C" void kernel_launch(void* const* d_in, const int* in_sizes, int n_in,
                              void* d_out, int out_size, void* d_ws, size_t ws_size,
                              hipStream_t stream) {
    const float* x   = (const float*)d_in[0];
    const float* Wq  = (const float*)d_in[1];
    const float* Wk  = (const float*)d_in[2];
    const float* Wv  = (const float*)d_in[3];
    const float* Wp  = (const float*)d_in[4];
    const float* bp  = (const float*)d_in[5];
    const float* W1  = (const float*)d_in[6];
    const float* b1  = (const float*)d_in[7];
    const float* W2  = (const float*)d_in[8];
    const float* b2  = (const float*)d_in[9];
    const float* g1  = (const float*)d_in[10];
    const float* be1 = (const float*)d_in[11];
    const float* g2  = (const float*)d_in[12];
    const float* be2 = (const float*)d_in[13];
    float* out = (float*)d_out;

    // workspace layout (112 MB), live-range aliased (same as r6):
    char* ws = (char*)d_ws;
    uint16_t* qkv   = (uint16_t*)(ws + 0);
    float*    P1p   = (float*)   (ws + 0);
    uint16_t* h1    = (uint16_t*)(ws + 0);
    uint16_t* obuf  = (uint16_t*)(ws + 25165824);
    uint16_t* xb    = (uint16_t*)(ws + 33554432);
    uint16_t* vT    = (uint16_t*)(ws + 33554432);
    uint16_t* x1b   = (uint16_t*)(ws + 33554432);
    float*    Q2    = (float*)   (ws + 33554432);
    uint16_t* wqkv  = (uint16_t*)(ws + 41943040);
    uint16_t* wpt   = (uint16_t*)(ws + 48234496);
    float*    resid = (float*)   (ws + 50331648);
    float*    Q1    = (float*)   (ws + 50331648);
    float*    x1f   = (float*)   (ws + 67108864);
    uint16_t* w1t   = (uint16_t*)(ws + 83886080);
    uint16_t* w2t   = (uint16_t*)(ws + 92274688);
    float*    Q3    = (float*)   (ws + 100663296);

    // step 1: pack / cast
    cast4_k<<<4096, 256, 0, stream>>>(x, xb);
    transpose_tile<<<dim3(32, 2, 16), dim3(32, 8), 0, stream>>>(Wq, wqkv,           1024, 64, 65536, 65536);
    transpose_tile<<<dim3(32, 2, 16), dim3(32, 8), 0, stream>>>(Wk, wqkv + 1048576, 1024, 64, 65536, 65536);
    transpose_tile<<<dim3(32, 2, 16), dim3(32, 8), 0, stream>>>(Wv, wqkv + 2097152, 1024, 64, 65536, 65536);
    transpose_tile<<<dim3(32, 32, 1),  dim3(32, 8), 0, stream>>>(Wp, wpt, 1024, 1024, 0, 0);
    transpose_tile<<<dim3(32, 128, 1), dim3(32, 8), 0, stream>>>(W1, w1t, 1024, 4096, 0, 0);
    transpose_tile<<<dim3(128, 32, 1), dim3(32, 8), 0, stream>>>(W2, w2t, 4096, 1024, 0, 0);

    // step 2: QKV projection, 8-phase 256^2 (192 blocks)
    gemm8_k<false, false, false, false><<<dim3(16, 12, 1), 512, 0, stream>>>(
        xb, wqkv, Cdim, Cdim, nullptr, qkv, nullptr, nullptr,
        nullptr, nullptr, nullptr, 3 * Cdim);
    // step 3: V^T pack
    vtrans_k<<<dim3(64, 2, 32), dim3(32, 8), 0, stream>>>(qkv, vT);
    // step 4: attention
    attn_k<<<dim3(16, 32), 256, 0, stream>>>(qkv, vT, obuf);
    // step 5: output projection, 128^2 split-K=2 (512 blocks)
    gemm_k<true, false, true, true><<<dim3(32, 8, 2), 256, 0, stream>>>(
        obuf, wpt, Cdim, Cdim / 2, resid, nullptr, bp, x, P1p, Cdim);
    // step 6: LN1 over (resid + P1p) -> x1f (fp32) + x1b (bf16)
    ln_k<<<Mdim, 256, 0, stream>>>(resid, P1p, nullptr, nullptr, g1, be1, x1f, x1b);
    // step 7: FFN1 relu(x1 @ W1 + b1) -> h1, 8-phase 256^2 (256 blocks = 1/CU)
    gemm8_k<true, true, false, false><<<dim3(16, 16, 1), 512, 0, stream>>>(
        x1b, w1t, Cdim, Cdim, nullptr, h1, b1, nullptr,
        nullptr, nullptr, nullptr, FFdim);
    // step 8: FFN2, 8-phase 256^2 split-K=4 (256 blocks = 1/CU, Kp=1024):
    //   kz=0 -> x1f += partial + b2 (in-place RMW) ; kz=1..3 -> Q1/Q2/Q3
    gemm8_k<true, false, true, true><<<dim3(16, 4, 4), 512, 0, stream>>>(
        h1, w2t, FFdim, FFdim / 4, x1f, nullptr, b2, x1f,
        Q1, Q2, Q3, Cdim);
    // step 9: LN2 over (x1f + Q1 + Q2 + Q3) -> out
    ln_k<<<Mdim, 256, 0, stream>>>(x1f, Q1, Q2, Q3, g2, be2, out, nullptr);
}

// Round 8
// 282.023 us; speedup vs baseline: 1.1767x; 1.0589x over previous
//
#include <hip/hip_runtime.h>
#include <cstdint>
#include <cstddef>

// ---------- types ----------
typedef __attribute__((ext_vector_type(8))) short short8;
typedef __attribute__((ext_vector_type(4))) short short4v;
typedef __attribute__((ext_vector_type(4))) float f32x4;
typedef __attribute__((ext_vector_type(2))) uint32_t u32x2;

#define Bdim 2
#define Tdim 2048
#define Cdim 1024
#define Hdim 16
#define HDdim 64
#define Mdim (Bdim*Tdim)   // 4096
#define FFdim (4*Cdim)     // 4096

__device__ __forceinline__ uint16_t f2bf(float f) {
    union { float f; uint32_t u; } v; v.f = f;
    uint32_t x = v.u;
    uint32_t r = x + 0x7FFFu + ((x >> 16) & 1u);
    return (uint16_t)(r >> 16);
}
__device__ __forceinline__ float bf2f(uint16_t h) {
    union { float f; uint32_t u; } v; v.u = ((uint32_t)h) << 16; return v.f;
}
// packed f32x2 -> bf16x2 (T12 primitive; no builtin on gfx950, inline asm)
__device__ __forceinline__ uint32_t cvtpk(float lo, float hi) {
    uint32_t r;
    asm("v_cvt_pk_bf16_f32 %0, %1, %2" : "=v"(r) : "v"(lo), "v"(hi));
    return r;
}

// async global->LDS, 16B per lane. dst must be wave-uniform base; HW adds lane*16.
__device__ __forceinline__ void gload_lds16(const uint16_t* g, uint16_t* l) {
    __builtin_amdgcn_global_load_lds(
        (const __attribute__((address_space(1))) void*)g,
        (__attribute__((address_space(3))) void*)l, 16, 0, 0);
}

#define RAW_BAR()   asm volatile("s_barrier" ::: "memory")
#define VMCNT(N)    asm volatile("s_waitcnt vmcnt(" #N ")" ::: "memory")

// ---------- elementwise cast f32 -> bf16 (vectorized x4) ----------
__global__ __launch_bounds__(256) void cast4_k(const float* __restrict__ in,
                                               uint16_t* __restrict__ out) {
    int i = (blockIdx.x * 256 + threadIdx.x) * 4;
    f32x4 v = *(const f32x4*)(in + i);
    short4v o;
#pragma unroll
    for (int j = 0; j < 4; ++j) o[j] = (short)f2bf(v[j]);
    *(short4v*)(out + i) = o;
}

// ---------- tiled transpose f32(R x Cc) -> bf16(Cc x R), batched ----------
__global__ __launch_bounds__(256) void transpose_tile(const float* __restrict__ in,
                                                      uint16_t* __restrict__ out,
                                                      int R, int Cc,
                                                      size_t ibs, size_t obs) {
    __shared__ uint16_t tile[32][33];
    const float* ip = in + (size_t)blockIdx.z * ibs;
    uint16_t* op = out + (size_t)blockIdx.z * obs;
    int r0 = blockIdx.x * 32, n0 = blockIdx.y * 32;
    int tx = threadIdx.x, ty = threadIdx.y;
#pragma unroll
    for (int i = 0; i < 4; ++i) {
        int r = ty + 8 * i;
        tile[r][tx] = f2bf(ip[(size_t)(r0 + r) * Cc + n0 + tx]);
    }
    __syncthreads();
#pragma unroll
    for (int i = 0; i < 4; ++i) {
        int n = ty + 8 * i;
        op[(size_t)(n0 + n) * R + r0 + tx] = tile[tx][n];
    }
}

// ---------- per-head V transpose: qkv V slice -> vT[bh][d=64][t=T] bf16 ------
// kv index is PERMUTED inside each 32-block: pi(16u+4g+r) = 8g+4u+r, so the
// attention PV fragment (kappa'(lg,j)) becomes ONE contiguous b128 LDS read.
__global__ __launch_bounds__(256) void vtrans_k(const uint16_t* __restrict__ qkv,
                                                uint16_t* __restrict__ vT) {
    __shared__ uint16_t tile[32][33];
    const int bh = blockIdx.z, b = bh >> 4, h = bh & 15;
    const uint16_t* vp = qkv + (size_t)b * Tdim * (3 * Cdim) + 2 * Cdim + h * HDdim;
    uint16_t* op = vT + (size_t)bh * HDdim * Tdim;
    const int t0 = blockIdx.x * 32, d0 = blockIdx.y * 32;
    const int tx = threadIdx.x, ty = threadIdx.y;
#pragma unroll
    for (int i = 0; i < 4; ++i) {
        int r = ty + 8 * i;
        tile[r][tx] = vp[(size_t)(t0 + r) * (3 * Cdim) + d0 + tx];
    }
    __syncthreads();
    // permuted column within the 32-block (t0 is a multiple of 32)
    const int tp = t0 + (((tx >> 2) & 3) << 3) + (((tx >> 4) & 1) << 2) + (tx & 3);
#pragma unroll
    for (int i = 0; i < 4; ++i) {
        int d = ty + 8 * i;
        op[(size_t)(d0 + d) * Tdim + tp] = tile[tx][d];
    }
}

// ================= 256x256 8-phase GEMM (T2+T3+T4+T5) =================
template<bool BIAS, bool RELU, bool RESID, bool OUTF>
__global__ __launch_bounds__(512, 2) void gemm8_k(const uint16_t* __restrict__ A,
                                                  const uint16_t* __restrict__ Bt,
                                                  int Kfull, int Kp,
                                                  float* outF,              // may alias resid
                                                  uint16_t* __restrict__ outB,
                                                  const float* __restrict__ bias,
                                                  const float* resid,       // may alias outF
                                                  float* __restrict__ outP1,
                                                  float* __restrict__ outP2,
                                                  float* __restrict__ outP3,
                                                  int N) {
    __shared__ uint16_t lds8[65536];   // 128 KiB
    const int bx = blockIdx.x, by = blockIdx.y, kz = blockIdx.z;
    const int tid = threadIdx.x;
    const int wave = tid >> 6, lane = tid & 63;
    const int lg = lane >> 4, lr = lane & 15, lr7 = lr & 7;
    const int wm = wave >> 2, wn = wave & 3;      // 2 x 4 wave grid
    const int NT = Kp >> 6;                        // K-tiles of 64

    const int aC = wm * 8192 + lr * 64;                                  // + p*16384
    const int bC = 32768 + (wn >> 1) * 8192 + (wn & 1) * 4096 + lr * 64; // + p*16384
    const int g0 = 8 * (lg ^ lr7);
    const int g1 = 8 * ((4 + lg) ^ lr7);

    const int srow = tid >> 3;
    const int scol = 8 * ((tid & 7) ^ (srow & 7));
    const uint16_t* aSrc = A + (size_t)(bx * 256 + srow) * Kfull + (size_t)kz * Kp + scol;
    const uint16_t* bSrc = Bt + (size_t)(by * 256 + srow) * Kfull + (size_t)kz * Kp + scol;
    const size_t r64 = (size_t)64 * Kfull, r128 = (size_t)128 * Kfull;

#define STG_A(pp, h, tt) do {                                                     \
        const uint16_t* s_ = aSrc + (h) * r128 + (size_t)(tt) * 64;               \
        uint16_t* d_ = &lds8[(pp) * 16384 + (h) * 8192 + wave * 512];             \
        gload_lds16(s_, d_); gload_lds16(s_ + r64, d_ + 4096);                    \
    } while (0)
#define STG_B(pp, h, tt) do {                                                     \
        const uint16_t* s_ = bSrc + (h) * r128 + (size_t)(tt) * 64;               \
        uint16_t* d_ = &lds8[32768 + (pp) * 16384 + (h) * 8192 + wave * 512];     \
        gload_lds16(s_, d_); gload_lds16(s_ + r64, d_ + 4096);                    \
    } while (0)
#define LD8(off) (*(const short8*)&lds8[off])
#define MM(M, Nn, AF, BF) acc[M][Nn] = __builtin_amdgcn_mfma_f32_16x16x32_bf16(AF, BF, acc[M][Nn], 0, 0, 0)

    f32x4 acc[8][4];
#pragma unroll
    for (int i = 0; i < 8; ++i)
#pragma unroll
        for (int j = 0; j < 4; ++j) acc[i][j] = (f32x4){0.f, 0.f, 0.f, 0.f};

    STG_B(0, 0, 0); STG_B(0, 1, 0); STG_A(0, 0, 0); STG_A(0, 1, 0);
    if (NT > 1) { STG_B(1, 0, 1); STG_B(1, 1, 1); STG_A(1, 0, 1); STG_A(1, 1, 1); VMCNT(8); }
    else VMCNT(0);
    RAW_BAR();

    short8 af[4][2], bf0[2][2], bf1[2][2];
    for (int t = 0; t < NT; ++t) {
        const int p = t & 1, p16 = p << 14;
        const bool nx1 = (t + 1 < NT), nx2 = (t + 2 < NT);
        // ---- phase 0 ----
#pragma unroll
        for (int m = 0; m < 4; ++m) {
            af[m][0] = LD8(p16 + aC + 1024 * m + g0);
            af[m][1] = LD8(p16 + aC + 1024 * m + g1);
        }
#pragma unroll
        for (int n = 0; n < 2; ++n) {
            bf0[n][0] = LD8(p16 + bC + 1024 * n + g0);
            bf0[n][1] = LD8(p16 + bC + 1024 * n + g1);
        }
        RAW_BAR();
        __builtin_amdgcn_s_setprio(1);
#pragma unroll
        for (int m = 0; m < 4; ++m)
#pragma unroll
            for (int n = 0; n < 2; ++n) { MM(m, n, af[m][0], bf0[n][0]); MM(m, n, af[m][1], bf0[n][1]); }
        __builtin_amdgcn_s_setprio(0);
        RAW_BAR();
        // ---- phase 1 ----
#pragma unroll
        for (int n = 0; n < 2; ++n) {
            bf1[n][0] = LD8(p16 + bC + 1024 * (n + 2) + g0);
            bf1[n][1] = LD8(p16 + bC + 1024 * (n + 2) + g1);
        }
        RAW_BAR();
        __builtin_amdgcn_s_setprio(1);
#pragma unroll
        for (int m = 0; m < 4; ++m)
#pragma unroll
            for (int n = 0; n < 2; ++n) { MM(m, n + 2, af[m][0], bf1[n][0]); MM(m, n + 2, af[m][1], bf1[n][1]); }
        __builtin_amdgcn_s_setprio(0);
        RAW_BAR();
        // ---- phase 2 ----
#pragma unroll
        for (int m = 0; m < 4; ++m) {
            af[m][0] = LD8(p16 + aC + 1024 * (m + 4) + g0);
            af[m][1] = LD8(p16 + aC + 1024 * (m + 4) + g1);
        }
        if (nx2) { STG_B(p, 0, t + 2); STG_B(p, 1, t + 2); }
        RAW_BAR();
        __builtin_amdgcn_s_setprio(1);
#pragma unroll
        for (int m = 0; m < 4; ++m)
#pragma unroll
            for (int n = 0; n < 2; ++n) { MM(m + 4, n + 2, af[m][0], bf1[n][0]); MM(m + 4, n + 2, af[m][1], bf1[n][1]); }
        __builtin_amdgcn_s_setprio(0);
        RAW_BAR();
        // ---- phase 3 ----
        if (nx2) { STG_A(p, 0, t + 2); STG_A(p, 1, t + 2); }
        RAW_BAR();
        __builtin_amdgcn_s_setprio(1);
#pragma unroll
        for (int m = 0; m < 4; ++m)
#pragma unroll
            for (int n = 0; n < 2; ++n) { MM(m + 4, n, af[m][0], bf0[n][0]); MM(m + 4, n, af[m][1], bf0[n][1]); }
        __builtin_amdgcn_s_setprio(0);
        if (nx1) {
            if (nx2) VMCNT(8); else VMCNT(0);
            RAW_BAR();
        }
    }
#undef STG_A
#undef STG_B
#undef LD8
#undef MM
    if (kz == 0) {
#pragma unroll
        for (int n = 0; n < 4; ++n) {
            const int col = (by << 8) + wn * 64 + 16 * n + lr;
            const float bv = BIAS ? bias[col] : 0.f;
#pragma unroll
            for (int m = 0; m < 8; ++m) {
#pragma unroll
                for (int r = 0; r < 4; ++r) {
                    const int row = (bx << 8) + wm * 128 + 16 * m + 4 * lg + r;
                    float v = acc[m][n][r] + bv;
                    if (RELU) v = fmaxf(v, 0.f);
                    if (RESID) v += resid[(size_t)row * N + col];
                    if (OUTF) outF[(size_t)row * N + col] = v;
                    else      outB[(size_t)row * N + col] = f2bf(v);
                }
            }
        }
    } else {
        float* op = (kz == 1) ? outP1 : (kz == 2) ? outP2 : outP3;
#pragma unroll
        for (int n = 0; n < 4; ++n) {
            const int col = (by << 8) + wn * 64 + 16 * n + lr;
#pragma unroll
            for (int m = 0; m < 8; ++m) {
#pragma unroll
                for (int r = 0; r < 4; ++r) {
                    const int row = (bx << 8) + wm * 128 + 16 * m + 4 * lg + r;
                    op[(size_t)row * N + col] = acc[m][n][r];
                }
            }
        }
    }
}

// ---------- 128^2 2-phase GEMM (kept for proj: NT too short for 8-phase) ----
template<bool BIAS, bool RELU, bool RESID, bool OUTF>
__global__ __launch_bounds__(256) void gemm_k(const uint16_t* __restrict__ A,
                                              const uint16_t* __restrict__ Bt,
                                              int Kfull, int Kp,
                                              float* outF,
                                              uint16_t* __restrict__ outB,
                                              const float* __restrict__ bias,
                                              const float* resid,
                                              float* __restrict__ outP1,
                                              int N) {
    __shared__ uint16_t As[2][128 * 32];
    __shared__ uint16_t Bs[2][128 * 32];
    const int bx = blockIdx.x, by = blockIdx.y, kz = blockIdx.z;
    const int tid = threadIdx.x;
    const int wave = tid >> 6, lane = tid & 63;
    const int lg = lane >> 4, lr = lane & 15;
    const int wm = (wave >> 1) << 6, wn = (wave & 1) << 6;
    const uint16_t* ag = A + (size_t)bx * 128 * Kfull + (size_t)(tid >> 2) * Kfull + (tid & 3) * 8 + (size_t)kz * Kp;
    const uint16_t* bg = Bt + (size_t)by * 128 * Kfull + (size_t)(tid >> 2) * Kfull + (tid & 3) * 8 + (size_t)kz * Kp;
    const size_t rstep = (size_t)64 * Kfull;
    const int db0 = wave * 512, db1 = 2048 + wave * 512;

    f32x4 acc[4][4];
#pragma unroll
    for (int i = 0; i < 4; ++i)
#pragma unroll
        for (int j = 0; j < 4; ++j) acc[i][j] = (f32x4){0.f, 0.f, 0.f, 0.f};

#define GSTAGE(bi, kk)                                     \
    do {                                                   \
        gload_lds16(ag + (kk), &As[bi][db0]);              \
        gload_lds16(ag + (kk) + rstep, &As[bi][db1]);      \
        gload_lds16(bg + (kk), &Bs[bi][db0]);              \
        gload_lds16(bg + (kk) + rstep, &Bs[bi][db1]);      \
    } while (0)

    GSTAGE(0, 0);
    __syncthreads();
    int cur = 0;
    for (int k0 = 0; k0 < Kp; k0 += 32) {
        if (k0 + 32 < Kp) GSTAGE(cur ^ 1, k0 + 32);
        short8 af[4], bfr[4];
#pragma unroll
        for (int m = 0; m < 4; ++m) af[m] = *(const short8*)(&As[cur][0] + (wm + 16 * m + lr) * 32 + 8 * lg);
#pragma unroll
        for (int n = 0; n < 4; ++n) bfr[n] = *(const short8*)(&Bs[cur][0] + (wn + 16 * n + lr) * 32 + 8 * lg);
#pragma unroll
        for (int m = 0; m < 4; ++m)
#pragma unroll
            for (int n = 0; n < 4; ++n)
                acc[m][n] = __builtin_amdgcn_mfma_f32_16x16x32_bf16(af[m], bfr[n], acc[m][n], 0, 0, 0);
        __syncthreads();
        cur ^= 1;
    }
#undef GSTAGE
    if (kz == 0) {
#pragma unroll
        for (int n = 0; n < 4; ++n) {
            const int col = (by << 7) + wn + 16 * n + lr;
            const float bv = BIAS ? bias[col] : 0.f;
#pragma unroll
            for (int m = 0; m < 4; ++m) {
#pragma unroll
                for (int r = 0; r < 4; ++r) {
                    const int row = (bx << 7) + wm + 16 * m + 4 * lg + r;
                    float v = acc[m][n][r] + bv;
                    if (RELU) v = fmaxf(v, 0.f);
                    if (RESID) v += resid[(size_t)row * N + col];
                    if (OUTF) outF[(size_t)row * N + col] = v;
                    else      outB[(size_t)row * N + col] = f2bf(v);
                }
            }
        }
    } else {
#pragma unroll
        for (int n = 0; n < 4; ++n) {
            const int col = (by << 7) + wn + 16 * n + lr;
#pragma unroll
            for (int m = 0; m < 4; ++m) {
#pragma unroll
                for (int r = 0; r < 4; ++r) {
                    const int row = (bx << 7) + wm + 16 * m + 4 * lg + r;
                    outP1[(size_t)row * N + col] = acc[m][n][r];
                }
            }
        }
    }
}

// ---------- flash attention: bh-major grid, diag-only mask, defer-max,
// cvt_pk softmax pack, contiguous permuted-V b128 fragments ----------
__global__ __launch_bounds__(256) void attn_k(const uint16_t* __restrict__ qkv,
                                              const uint16_t* __restrict__ vT,
                                              uint16_t* __restrict__ o) {
    __shared__ uint16_t Kb[2][64 * 64];
    __shared__ uint16_t Vb[2][64 * 64];
    const int tid = threadIdx.x;
    const int wave = tid >> 6, lane = tid & 63;
    const int lg = lane >> 4, lr = lane & 15, lr7 = lr & 7;
    // bh on blockIdx.x: with 32 % 8 == 0 round-robin, all blocks of one bh
    // land on one XCD -> K/V (0.5 MB/bh) stays L2-resident.
    const int bh = blockIdx.x, b = bh >> 4, h = bh & 15;
    const size_t rs = 3 * Cdim;
    const uint16_t* qp = qkv + (size_t)b * Tdim * rs + (size_t)h * HDdim;
    const uint16_t* kp = qp + Cdim;
    const uint16_t* vtp = vT + (size_t)bh * HDdim * Tdim;

    const int s0 = tid, s1 = tid + 256;
    const int r0v = s0 >> 3, c0v = ((s0 & 7) ^ (r0v & 7)) << 3;
    const int r1v = s1 >> 3, c1v = ((s1 & 7) ^ (r1v & 7)) << 3;
    const int db0 = wave * 512, db1 = 2048 + wave * 512;

#define STAGE(bufi, kvb)                                                        \
    do {                                                                        \
        gload_lds16(kp + (size_t)((kvb) + r0v) * rs + c0v, &Kb[bufi][db0]);     \
        gload_lds16(kp + (size_t)((kvb) + r1v) * rs + c1v, &Kb[bufi][db1]);     \
        gload_lds16(vtp + (size_t)r0v * Tdim + (kvb) + c0v, &Vb[bufi][db0]);    \
        gload_lds16(vtp + (size_t)r1v * Tdim + (kvb) + c1v, &Vb[bufi][db1]);    \
    } while (0)

    const int tiles[2] = {(int)blockIdx.y, 31 - (int)blockIdx.y};

    for (int ti = 0; ti < 2; ++ti) {
        const int tx = tiles[ti];
        const int q0 = tx << 6;
        const int nch = tx + 1;
        const int qrow = q0 + 16 * wave + lr;

        short8 qf[2];
#pragma unroll
        for (int c = 0; c < 2; ++c) {
            short8 raw = *(const short8*)(qp + (size_t)qrow * rs + 32 * c + 8 * lg);
#pragma unroll
            for (int j = 0; j < 8; ++j)
                qf[c][j] = (short)f2bf(bf2f((uint16_t)raw[j]) * 0.125f);
        }

        float m_run = -__builtin_inff(), l_run = 0.f;
        f32x4 oacc[4];
#pragma unroll
        for (int t = 0; t < 4; ++t) oacc[t] = (f32x4){0.f, 0.f, 0.f, 0.f};

        STAGE(0, 0);
        __syncthreads();
        int cur = 0;
        for (int ch = 0; ch < nch; ++ch) {
            if (ch + 1 < nch) STAGE(cur ^ 1, 64 * (ch + 1));
            const int kvb = 64 * ch;
            const char* Kc = (const char*)&Kb[cur][0];
            const char* Vc = (const char*)&Vb[cur][0];
            short8 kf[4][2];
#pragma unroll
            for (int u = 0; u < 4; ++u)
#pragma unroll
                for (int c = 0; c < 2; ++c)
                    kf[u][c] = *(const short8*)(Kc + (16 * u + lr) * 128 +
                                                (((lg + 4 * c) ^ lr7) << 4));
            f32x4 s4[4];
            __builtin_amdgcn_s_setprio(1);
#pragma unroll
            for (int u = 0; u < 4; ++u) {
                f32x4 z = (f32x4){0.f, 0.f, 0.f, 0.f};
                z = __builtin_amdgcn_mfma_f32_16x16x32_bf16(kf[u][0], qf[0], z, 0, 0, 0);
                z = __builtin_amdgcn_mfma_f32_16x16x32_bf16(kf[u][1], qf[1], z, 0, 0, 0);
                s4[u] = z;
            }
            __builtin_amdgcn_s_setprio(0);
            // ---- softmax: mask only the diagonal chunk ----
            float p[4][4];
            float mx;
            if (ch + 1 == nch) {
                mx = -__builtin_inff();
#pragma unroll
                for (int u = 0; u < 4; ++u)
#pragma unroll
                    for (int r = 0; r < 4; ++r) {
                        int kv = kvb + 16 * u + 4 * lg + r;
                        float sv = (kv <= qrow) ? s4[u][r] : -__builtin_inff();
                        p[u][r] = sv;
                        mx = fmaxf(mx, sv);
                    }
            } else {
#pragma unroll
                for (int u = 0; u < 4; ++u)
#pragma unroll
                    for (int r = 0; r < 4; ++r) p[u][r] = s4[u][r];
                f32x4 m4;
#pragma unroll
                for (int r = 0; r < 4; ++r)
                    m4[r] = fmaxf(fmaxf(s4[0][r], s4[1][r]), fmaxf(s4[2][r], s4[3][r]));
                mx = fmaxf(fmaxf(m4[0], m4[1]), fmaxf(m4[2], m4[3]));
            }
            mx = fmaxf(mx, __shfl_xor(mx, 16));
            mx = fmaxf(mx, __shfl_xor(mx, 32));
            // ---- defer-max (T13, THR=8): skip rescale when max barely grew ----
            if (!__all(mx <= m_run + 8.f)) {
                const float m_new = fmaxf(m_run, mx);
                const float alpha = __expf(m_run - m_new);   // first chunk: exp(-inf)=0
#pragma unroll
                for (int t = 0; t < 4; ++t)
#pragma unroll
                    for (int r = 0; r < 4; ++r) oacc[t][r] *= alpha;
                l_run *= alpha;
                m_run = m_new;
            }
            float ps = 0.f;
#pragma unroll
            for (int u = 0; u < 4; ++u)
#pragma unroll
                for (int r = 0; r < 4; ++r) {
                    float e = __expf(p[u][r] - m_run);
                    p[u][r] = e; ps += e;
                }
            ps += __shfl_xor(ps, 16);
            ps += __shfl_xor(ps, 32);
            l_run += ps;
            // ---- P -> bf16 via v_cvt_pk (8 instrs replace 16 f2bf) ----
            short8 pb[2];
#pragma unroll
            for (int hh = 0; hh < 2; ++hh) {
                union { uint32_t w[4]; short8 v; } q_;
                q_.w[0] = cvtpk(p[2 * hh][0], p[2 * hh][1]);
                q_.w[1] = cvtpk(p[2 * hh][2], p[2 * hh][3]);
                q_.w[2] = cvtpk(p[2 * hh + 1][0], p[2 * hh + 1][1]);
                q_.w[3] = cvtpk(p[2 * hh + 1][2], p[2 * hh + 1][3]);
                pb[hh] = q_.v;
            }
            // ---- PV: permuted V layout -> one b128 per fragment ----
            __builtin_amdgcn_s_setprio(1);
#pragma unroll
            for (int t = 0; t < 4; ++t) {
                const int vbase = (16 * t + lr) * 128;
                f32x4 oa = oacc[t];
#pragma unroll
                for (int hh = 0; hh < 2; ++hh) {
                    short8 vf = *(const short8*)(Vc + vbase + (((4 * hh + lg) ^ lr7) << 4));
                    oa = __builtin_amdgcn_mfma_f32_16x16x32_bf16(vf, pb[hh], oa, 0, 0, 0);
                }
                oacc[t] = oa;
            }
            __builtin_amdgcn_s_setprio(0);
            __syncthreads();
            cur ^= 1;
        }
        // epilogue: packed bf16, 8B stores
        const float inv = 1.f / l_run;
        uint16_t* orow = o + (size_t)(b * Tdim + qrow) * Cdim + h * HDdim;
#pragma unroll
        for (int t = 0; t < 4; ++t) {
            u32x2 wv;
            wv[0] = cvtpk(oacc[t][0] * inv, oacc[t][1] * inv);
            wv[1] = cvtpk(oacc[t][2] * inv, oacc[t][3] * inv);
            *(u32x2*)(orow + 16 * t + 4 * lg) = wv;
        }
        __syncthreads();
    }
#undef STAGE
}

// ---------- LayerNorm over rows of 1024: in (+ up to 3 partials) summed ----------
__global__ __launch_bounds__(256) void ln_k(const float* __restrict__ in,
                                            const float* __restrict__ in2,
                                            const float* __restrict__ in3,
                                            const float* __restrict__ in4,
                                            const float* __restrict__ g,
                                            const float* __restrict__ be,
                                            float* __restrict__ outF,
                                            uint16_t* __restrict__ outB) {
    const int row = blockIdx.x, tid = threadIdx.x;
    const size_t base = (size_t)row * Cdim + tid * 4;
    f32x4 xv = *(const f32x4*)(in + base);
    if (in2) {
        f32x4 yv = *(const f32x4*)(in2 + base);
#pragma unroll
        for (int j = 0; j < 4; ++j) xv[j] += yv[j];
    }
    if (in3) {
        f32x4 yv = *(const f32x4*)(in3 + base);
#pragma unroll
        for (int j = 0; j < 4; ++j) xv[j] += yv[j];
    }
    if (in4) {
        f32x4 yv = *(const f32x4*)(in4 + base);
#pragma unroll
        for (int j = 0; j < 4; ++j) xv[j] += yv[j];
    }
    float s = xv[0] + xv[1] + xv[2] + xv[3];
    float q = xv[0] * xv[0] + xv[1] * xv[1] + xv[2] * xv[2] + xv[3] * xv[3];
#pragma unroll
    for (int off = 1; off < 64; off <<= 1) { s += __shfl_xor(s, off); q += __shfl_xor(q, off); }
    __shared__ float sm[4], sq[4];
    if ((tid & 63) == 0) { sm[tid >> 6] = s; sq[tid >> 6] = q; }
    __syncthreads();
    s = sm[0] + sm[1] + sm[2] + sm[3];
    q = sq[0] + sq[1] + sq[2] + sq[3];
    const float mu = s * (1.f / 1024.f);
    const float var = q * (1.f / 1024.f) - mu * mu;
    const float rstd = rsqrtf(var + 1e-5f);
#pragma unroll
    for (int j = 0; j < 4; ++j) {
        int col = tid * 4 + j;
        float y = (xv[j] - mu) * rstd * g[col] + be[col];
        if (outF) outF[(size_t)row * Cdim + col] = y;
        if (outB) outB[(size_t)row * Cdim + col] = f2bf(y);
    }
}

// ---------- launch ----------
extern "C" void kernel_launch(void* const* d_in, const int* in_sizes, int n_in,
                              void* d_out, int out_size, void* d_ws, size_t ws_size,
                              hipStream_t stream) {
    const float* x   = (const float*)d_in[0];
    const float* Wq  = (const float*)d_in[1];
    const float* Wk  = (const float*)d_in[2];
    const float* Wv  = (const float*)d_in[3];
    const float* Wp  = (const float*)d_in[4];
    const float* bp  = (const float*)d_in[5];
    const float* W1  = (const float*)d_in[6];
    const float* b1  = (const float*)d_in[7];
    const float* W2  = (const float*)d_in[8];
    const float* b2  = (const float*)d_in[9];
    const float* g1  = (const float*)d_in[10];
    const float* be1 = (const float*)d_in[11];
    const float* g2  = (const float*)d_in[12];
    const float* be2 = (const float*)d_in[13];
    float* out = (float*)d_out;

    // workspace layout (112 MB), live-range aliased (same as r6/r7):
    char* ws = (char*)d_ws;
    uint16_t* qkv   = (uint16_t*)(ws + 0);
    float*    P1p   = (float*)   (ws + 0);
    uint16_t* h1    = (uint16_t*)(ws + 0);
    uint16_t* obuf  = (uint16_t*)(ws + 25165824);
    uint16_t* xb    = (uint16_t*)(ws + 33554432);
    uint16_t* vT    = (uint16_t*)(ws + 33554432);
    uint16_t* x1b   = (uint16_t*)(ws + 33554432);
    float*    Q2    = (float*)   (ws + 33554432);
    uint16_t* wqkv  = (uint16_t*)(ws + 41943040);
    uint16_t* wpt   = (uint16_t*)(ws + 48234496);
    float*    resid = (float*)   (ws + 50331648);
    float*    Q1    = (float*)   (ws + 50331648);
    float*    x1f   = (float*)   (ws + 67108864);
    uint16_t* w1t   = (uint16_t*)(ws + 83886080);
    uint16_t* w2t   = (uint16_t*)(ws + 92274688);
    float*    Q3    = (float*)   (ws + 100663296);

    // step 1: pack / cast
    cast4_k<<<4096, 256, 0, stream>>>(x, xb);
    transpose_tile<<<dim3(32, 2, 16), dim3(32, 8), 0, stream>>>(Wq, wqkv,           1024, 64, 65536, 65536);
    transpose_tile<<<dim3(32, 2, 16), dim3(32, 8), 0, stream>>>(Wk, wqkv + 1048576, 1024, 64, 65536, 65536);
    transpose_tile<<<dim3(32, 2, 16), dim3(32, 8), 0, stream>>>(Wv, wqkv + 2097152, 1024, 64, 65536, 65536);
    transpose_tile<<<dim3(32, 32, 1),  dim3(32, 8), 0, stream>>>(Wp, wpt, 1024, 1024, 0, 0);
    transpose_tile<<<dim3(32, 128, 1), dim3(32, 8), 0, stream>>>(W1, w1t, 1024, 4096, 0, 0);
    transpose_tile<<<dim3(128, 32, 1), dim3(32, 8), 0, stream>>>(W2, w2t, 4096, 1024, 0, 0);

    // step 2: QKV projection, 8-phase 256^2 (192 blocks)
    gemm8_k<false, false, false, false><<<dim3(16, 12, 1), 512, 0, stream>>>(
        xb, wqkv, Cdim, Cdim, nullptr, qkv, nullptr, nullptr,
        nullptr, nullptr, nullptr, 3 * Cdim);
    // step 3: V^T pack (kv-permuted within 32-blocks)
    vtrans_k<<<dim3(64, 2, 32), dim3(32, 8), 0, stream>>>(qkv, vT);
    // step 4: attention (bh-major grid for XCD L2 locality)
    attn_k<<<dim3(32, 16), 256, 0, stream>>>(qkv, vT, obuf);
    // step 5: output projection, 128^2 split-K=2 (512 blocks)
    gemm_k<true, false, true, true><<<dim3(32, 8, 2), 256, 0, stream>>>(
        obuf, wpt, Cdim, Cdim / 2, resid, nullptr, bp, x, P1p, Cdim);
    // step 6: LN1 over (resid + P1p) -> x1f (fp32) + x1b (bf16)
    ln_k<<<Mdim, 256, 0, stream>>>(resid, P1p, nullptr, nullptr, g1, be1, x1f, x1b);
    // step 7: FFN1 relu(x1 @ W1 + b1) -> h1, 8-phase 256^2 (256 blocks = 1/CU)
    gemm8_k<true, true, false, false><<<dim3(16, 16, 1), 512, 0, stream>>>(
        x1b, w1t, Cdim, Cdim, nullptr, h1, b1, nullptr,
        nullptr, nullptr, nullptr, FFdim);
    // step 8: FFN2, 8-phase 256^2 split-K=4 (256 blocks = 1/CU, Kp=1024):
    gemm8_k<true, false, true, true><<<dim3(16, 4, 4), 512, 0, stream>>>(
        h1, w2t, FFdim, FFdim / 4, x1f, nullptr, b2, x1f,
        Q1, Q2, Q3, Cdim);
    // step 9: LN2 over (x1f + Q1 + Q2 + Q3) -> out
    ln_k<<<Mdim, 256, 0, stream>>>(x1f, Q1, Q2, Q3, g2, be2, out, nullptr);
}

// Round 9
// 275.044 us; speedup vs baseline: 1.2066x; 1.0254x over previous
//
#include <hip/hip_runtime.h>
#include <cstdint>
#include <cstddef>

// ---------- types ----------
typedef __attribute__((ext_vector_type(8))) short short8;
typedef __attribute__((ext_vector_type(4))) short short4v;
typedef __attribute__((ext_vector_type(4))) float f32x4;
typedef __attribute__((ext_vector_type(2))) uint32_t u32x2;

#define Bdim 2
#define Tdim 2048
#define Cdim 1024
#define Hdim 16
#define HDdim 64
#define Mdim (Bdim*Tdim)   // 4096
#define FFdim (4*Cdim)     // 4096

__device__ __forceinline__ uint16_t f2bf(float f) {
    union { float f; uint32_t u; } v; v.f = f;
    uint32_t x = v.u;
    uint32_t r = x + 0x7FFFu + ((x >> 16) & 1u);
    return (uint16_t)(r >> 16);
}
__device__ __forceinline__ float bf2f(uint16_t h) {
    union { float f; uint32_t u; } v; v.u = ((uint32_t)h) << 16; return v.f;
}
// packed f32x2 -> bf16x2 (T12 primitive; no builtin on gfx950, inline asm)
__device__ __forceinline__ uint32_t cvtpk(float lo, float hi) {
    uint32_t r;
    asm("v_cvt_pk_bf16_f32 %0, %1, %2" : "=v"(r) : "v"(lo), "v"(hi));
    return r;
}

// async global->LDS, 16B per lane. dst must be wave-uniform base; HW adds lane*16.
__device__ __forceinline__ void gload_lds16(const uint16_t* g, uint16_t* l) {
    __builtin_amdgcn_global_load_lds(
        (const __attribute__((address_space(1))) void*)g,
        (__attribute__((address_space(3))) void*)l, 16, 0, 0);
}

#define RAW_BAR()   asm volatile("s_barrier" ::: "memory")
#define VMCNT(N)    asm volatile("s_waitcnt vmcnt(" #N ")" ::: "memory")

// ---------- elementwise cast f32 -> bf16 (vectorized x4) ----------
__global__ __launch_bounds__(256) void cast4_k(const float* __restrict__ in,
                                               uint16_t* __restrict__ out) {
    int i = (blockIdx.x * 256 + threadIdx.x) * 4;
    f32x4 v = *(const f32x4*)(in + i);
    short4v o;
#pragma unroll
    for (int j = 0; j < 4; ++j) o[j] = (short)f2bf(v[j]);
    *(short4v*)(out + i) = o;
}

// ---------- tiled transpose f32(R x Cc) -> bf16(Cc x R), batched ----------
__global__ __launch_bounds__(256) void transpose_tile(const float* __restrict__ in,
                                                      uint16_t* __restrict__ out,
                                                      int R, int Cc,
                                                      size_t ibs, size_t obs) {
    __shared__ uint16_t tile[32][33];
    const float* ip = in + (size_t)blockIdx.z * ibs;
    uint16_t* op = out + (size_t)blockIdx.z * obs;
    int r0 = blockIdx.x * 32, n0 = blockIdx.y * 32;
    int tx = threadIdx.x, ty = threadIdx.y;
#pragma unroll
    for (int i = 0; i < 4; ++i) {
        int r = ty + 8 * i;
        tile[r][tx] = f2bf(ip[(size_t)(r0 + r) * Cc + n0 + tx]);
    }
    __syncthreads();
#pragma unroll
    for (int i = 0; i < 4; ++i) {
        int n = ty + 8 * i;
        op[(size_t)(n0 + n) * R + r0 + tx] = tile[tx][n];
    }
}

// ---------- per-head V transpose: qkv V slice -> vT[bh][d=64][t=T] bf16 ------
// kv index is PERMUTED inside each 32-block: pi(16u+4g+r) = 8g+4u+r, so the
// attention PV fragment (kappa'(lg,j)) becomes ONE contiguous b128 LDS read.
__global__ __launch_bounds__(256) void vtrans_k(const uint16_t* __restrict__ qkv,
                                                uint16_t* __restrict__ vT) {
    __shared__ uint16_t tile[32][33];
    const int bh = blockIdx.z, b = bh >> 4, h = bh & 15;
    const uint16_t* vp = qkv + (size_t)b * Tdim * (3 * Cdim) + 2 * Cdim + h * HDdim;
    uint16_t* op = vT + (size_t)bh * HDdim * Tdim;
    const int t0 = blockIdx.x * 32, d0 = blockIdx.y * 32;
    const int tx = threadIdx.x, ty = threadIdx.y;
#pragma unroll
    for (int i = 0; i < 4; ++i) {
        int r = ty + 8 * i;
        tile[r][tx] = vp[(size_t)(t0 + r) * (3 * Cdim) + d0 + tx];
    }
    __syncthreads();
    // permuted column within the 32-block (t0 is a multiple of 32)
    const int tp = t0 + (((tx >> 2) & 3) << 3) + (((tx >> 4) & 1) << 2) + (tx & 3);
#pragma unroll
    for (int i = 0; i < 4; ++i) {
        int d = ty + 8 * i;
        op[(size_t)(d0 + d) * Tdim + tp] = tile[tx][d];
    }
}

// ============ 256x256 GEMM, buffer-rotation pipeline (2 barriers/K-tile) =====
// C = A(M x Kfull) * Bt(N x Kfull)^T. 512 thr = 8 waves (2M x 4N), BK=64.
// LDS 160 KiB: A double-buffer (2 x 32 KB) + B TRIPLE-buffer (3 x 32 KB).
// Per K-tile t: read A(16 b128)+B-half(8); stage B(t+2)->(t+2)%3 (no hazard:
// never the live buffer); 32 MFMA; BAR (A reads provably retired -- MFMAs
// consumed them); stage A(t+2) into just-freed A buf; read B 2nd half; 32
// MFMA; vmcnt(8) (t+1 landed, t+2 stays in flight) + BAR. Compiler emits
// counted lgkmcnt for LDS->MFMA (m97-verified); waves drift within halves.
template<bool BIAS, bool RELU, bool RESID, bool OUTF>
__global__ __launch_bounds__(512, 2) void gemm8_k(const uint16_t* __restrict__ A,
                                                  const uint16_t* __restrict__ Bt,
                                                  int Kfull, int Kp,
                                                  float* outF,              // may alias resid
                                                  uint16_t* __restrict__ outB,
                                                  const float* __restrict__ bias,
                                                  const float* resid,       // may alias outF
                                                  float* __restrict__ outP1,
                                                  float* __restrict__ outP2,
                                                  float* __restrict__ outP3,
                                                  int N) {
    __shared__ uint16_t lds8[81920];   // 160 KiB: A[2] @ 0,16384 ; B[3] @ 32768+16384*j
    const int bx = blockIdx.x, by = blockIdx.y, kz = blockIdx.z;
    const int tid = threadIdx.x;
    const int wave = tid >> 6, lane = tid & 63;
    const int lg = lane >> 4, lr = lane & 15, lr7 = lr & 7;
    const int wm = wave >> 2, wn = wave & 3;      // 2 x 4 wave grid
    const int NT = Kp >> 6;                        // K-tiles of 64 (>= 4 everywhere)

    // ds_read addressing (element units; 8 el = one 16B swizzle group)
    const int aC = wm * 8192 + lr * 64;                                  // + abuf*16384
    const int bC = (wn >> 1) * 8192 + (wn & 1) * 4096 + lr * 64;         // + 32768 + bbuf*16384
    const int g0 = 8 * (lg ^ lr7);
    const int g1 = 8 * ((4 + lg) ^ lr7);

    // stage addressing: thread covers LDS slot s=tid per gload (swizzled source)
    const int srow = tid >> 3;
    const int scol = 8 * ((tid & 7) ^ (srow & 7));
    const uint16_t* aSrc = A + (size_t)(bx * 256 + srow) * Kfull + (size_t)kz * Kp + scol;
    const uint16_t* bSrc = Bt + (size_t)(by * 256 + srow) * Kfull + (size_t)kz * Kp + scol;
    const size_t r64 = (size_t)64 * Kfull, r128 = (size_t)128 * Kfull;

#define STG_A(ab, tt) do {                                                        \
        _Pragma("unroll")                                                         \
        for (int h_ = 0; h_ < 2; ++h_) {                                          \
            const uint16_t* s_ = aSrc + h_ * r128 + (size_t)(tt) * 64;            \
            uint16_t* d_ = &lds8[(ab) + h_ * 8192 + wave * 512];                  \
            gload_lds16(s_, d_); gload_lds16(s_ + r64, d_ + 4096);                \
        }                                                                         \
    } while (0)
#define STG_B(bb, tt) do {                                                        \
        _Pragma("unroll")                                                         \
        for (int h_ = 0; h_ < 2; ++h_) {                                          \
            const uint16_t* s_ = bSrc + h_ * r128 + (size_t)(tt) * 64;            \
            uint16_t* d_ = &lds8[32768 + (bb) * 16384 + h_ * 8192 + wave * 512];  \
            gload_lds16(s_, d_); gload_lds16(s_ + r64, d_ + 4096);                \
        }                                                                         \
    } while (0)
#define LD8(off) (*(const short8*)&lds8[off])
#define MM(M, Nn, AF, BF) acc[M][Nn] = __builtin_amdgcn_mfma_f32_16x16x32_bf16(AF, BF, acc[M][Nn], 0, 0, 0)

    f32x4 acc[8][4];
#pragma unroll
    for (int i = 0; i < 8; ++i)
#pragma unroll
        for (int j = 0; j < 4; ++j) acc[i][j] = (f32x4){0.f, 0.f, 0.f, 0.f};

    // prologue: stage tiles 0 and 1 (A parity 0/1, B slots 0/1); oldest 8 = t0
    STG_B(0, 0); STG_A(0, 0); STG_B(1, 1); STG_A(16384, 1);
    VMCNT(8);
    RAW_BAR();

    int bsel = 0;         // B slot of tile t
    for (int t = 0; t < NT; ++t) {
        const int pa = (t & 1) << 14;              // A buf element base
        const int pbb = 32768 + bsel * 16384;      // B buf element base
        const int bsel2 = bsel >= 1 ? bsel - 1 : 2;  // (t+2)%3 given bsel=t%3... see note
        const bool nx1 = (t + 1 < NT), nx2 = (t + 2 < NT);

        // ---- half 1: all A frags + B n0-1 ----
        short8 af[8][2], bf[2][2];
#pragma unroll
        for (int m = 0; m < 8; ++m) {
            af[m][0] = LD8(pa + aC + 1024 * m + g0);
            af[m][1] = LD8(pa + aC + 1024 * m + g1);
        }
#pragma unroll
        for (int n = 0; n < 2; ++n) {
            bf[n][0] = LD8(pbb + bC + 1024 * n + g0);
            bf[n][1] = LD8(pbb + bC + 1024 * n + g1);
        }
        if (nx2) STG_B(bsel2, t + 2);   // (t+2)%3: never the live or next B buf
        __builtin_amdgcn_s_setprio(1);
#pragma unroll
        for (int m = 0; m < 8; ++m)
#pragma unroll
            for (int n = 0; n < 2; ++n) MM(m, n, af[m][0], bf[n][0]);
#pragma unroll
        for (int m = 0; m < 8; ++m)
#pragma unroll
            for (int n = 0; n < 2; ++n) MM(m, n, af[m][1], bf[n][1]);
        __builtin_amdgcn_s_setprio(0);
        RAW_BAR();   // every wave's A(+B1st) ds_reads retired (MFMAs consumed them)

        // ---- half 2: stage A(t+2) into just-freed A buf; B n2-3 ----
        if (nx2) STG_A(pa, t + 2);      // (t+2)&1 == t&1
        short8 bg2[2][2];
#pragma unroll
        for (int n = 0; n < 2; ++n) {
            bg2[n][0] = LD8(pbb + bC + 1024 * (n + 2) + g0);
            bg2[n][1] = LD8(pbb + bC + 1024 * (n + 2) + g1);
        }
        __builtin_amdgcn_s_setprio(1);
#pragma unroll
        for (int m = 0; m < 8; ++m)
#pragma unroll
            for (int n = 0; n < 2; ++n) MM(m, n + 2, af[m][0], bg2[n][0]);
#pragma unroll
        for (int m = 0; m < 8; ++m)
#pragma unroll
            for (int n = 0; n < 2; ++n) MM(m, n + 2, af[m][1], bg2[n][1]);
        __builtin_amdgcn_s_setprio(0);

        // ---- boundary: t+1's 8 loads must be landed; keep t+2's in flight ----
        if (nx1) {
            if (nx2) VMCNT(8); else VMCNT(0);
            RAW_BAR();
        }
        bsel = bsel + 1 >= 3 ? 0 : bsel + 1;
    }
#undef STG_A
#undef STG_B
#undef LD8
#undef MM
    // epilogue: C/D layout col=lane&15, row=4*(lane>>4)+reg
    if (kz == 0) {
#pragma unroll
        for (int n = 0; n < 4; ++n) {
            const int col = (by << 8) + wn * 64 + 16 * n + lr;
            const float bv = BIAS ? bias[col] : 0.f;
#pragma unroll
            for (int m = 0; m < 8; ++m) {
#pragma unroll
                for (int r = 0; r < 4; ++r) {
                    const int row = (bx << 8) + wm * 128 + 16 * m + 4 * lg + r;
                    float v = acc[m][n][r] + bv;
                    if (RELU) v = fmaxf(v, 0.f);
                    if (RESID) v += resid[(size_t)row * N + col];
                    if (OUTF) outF[(size_t)row * N + col] = v;
                    else      outB[(size_t)row * N + col] = f2bf(v);
                }
            }
        }
    } else {
        float* op = (kz == 1) ? outP1 : (kz == 2) ? outP2 : outP3;
#pragma unroll
        for (int n = 0; n < 4; ++n) {
            const int col = (by << 8) + wn * 64 + 16 * n + lr;
#pragma unroll
            for (int m = 0; m < 8; ++m) {
#pragma unroll
                for (int r = 0; r < 4; ++r) {
                    const int row = (bx << 8) + wm * 128 + 16 * m + 4 * lg + r;
                    op[(size_t)row * N + col] = acc[m][n][r];
                }
            }
        }
    }
}

// ---------- 128^2 2-phase GEMM (kept for proj: NT too short for pipeline) ----
template<bool BIAS, bool RELU, bool RESID, bool OUTF>
__global__ __launch_bounds__(256) void gemm_k(const uint16_t* __restrict__ A,
                                              const uint16_t* __restrict__ Bt,
                                              int Kfull, int Kp,
                                              float* outF,
                                              uint16_t* __restrict__ outB,
                                              const float* __restrict__ bias,
                                              const float* resid,
                                              float* __restrict__ outP1,
                                              int N) {
    __shared__ uint16_t As[2][128 * 32];
    __shared__ uint16_t Bs[2][128 * 32];
    const int bx = blockIdx.x, by = blockIdx.y, kz = blockIdx.z;
    const int tid = threadIdx.x;
    const int wave = tid >> 6, lane = tid & 63;
    const int lg = lane >> 4, lr = lane & 15;
    const int wm = (wave >> 1) << 6, wn = (wave & 1) << 6;
    const uint16_t* ag = A + (size_t)bx * 128 * Kfull + (size_t)(tid >> 2) * Kfull + (tid & 3) * 8 + (size_t)kz * Kp;
    const uint16_t* bg = Bt + (size_t)by * 128 * Kfull + (size_t)(tid >> 2) * Kfull + (tid & 3) * 8 + (size_t)kz * Kp;
    const size_t rstep = (size_t)64 * Kfull;
    const int db0 = wave * 512, db1 = 2048 + wave * 512;

    f32x4 acc[4][4];
#pragma unroll
    for (int i = 0; i < 4; ++i)
#pragma unroll
        for (int j = 0; j < 4; ++j) acc[i][j] = (f32x4){0.f, 0.f, 0.f, 0.f};

#define GSTAGE(bi, kk)                                     \
    do {                                                   \
        gload_lds16(ag + (kk), &As[bi][db0]);              \
        gload_lds16(ag + (kk) + rstep, &As[bi][db1]);      \
        gload_lds16(bg + (kk), &Bs[bi][db0]);              \
        gload_lds16(bg + (kk) + rstep, &Bs[bi][db1]);      \
    } while (0)

    GSTAGE(0, 0);
    __syncthreads();
    int cur = 0;
    for (int k0 = 0; k0 < Kp; k0 += 32) {
        if (k0 + 32 < Kp) GSTAGE(cur ^ 1, k0 + 32);
        short8 af[4], bfr[4];
#pragma unroll
        for (int m = 0; m < 4; ++m) af[m] = *(const short8*)(&As[cur][0] + (wm + 16 * m + lr) * 32 + 8 * lg);
#pragma unroll
        for (int n = 0; n < 4; ++n) bfr[n] = *(const short8*)(&Bs[cur][0] + (wn + 16 * n + lr) * 32 + 8 * lg);
#pragma unroll
        for (int m = 0; m < 4; ++m)
#pragma unroll
            for (int n = 0; n < 4; ++n)
                acc[m][n] = __builtin_amdgcn_mfma_f32_16x16x32_bf16(af[m], bfr[n], acc[m][n], 0, 0, 0);
        __syncthreads();
        cur ^= 1;
    }
#undef GSTAGE
    if (kz == 0) {
#pragma unroll
        for (int n = 0; n < 4; ++n) {
            const int col = (by << 7) + wn + 16 * n + lr;
            const float bv = BIAS ? bias[col] : 0.f;
#pragma unroll
            for (int m = 0; m < 4; ++m) {
#pragma unroll
                for (int r = 0; r < 4; ++r) {
                    const int row = (bx << 7) + wm + 16 * m + 4 * lg + r;
                    float v = acc[m][n][r] + bv;
                    if (RELU) v = fmaxf(v, 0.f);
                    if (RESID) v += resid[(size_t)row * N + col];
                    if (OUTF) outF[(size_t)row * N + col] = v;
                    else      outB[(size_t)row * N + col] = f2bf(v);
                }
            }
        }
    } else {
#pragma unroll
        for (int n = 0; n < 4; ++n) {
            const int col = (by << 7) + wn + 16 * n + lr;
#pragma unroll
            for (int m = 0; m < 4; ++m) {
#pragma unroll
                for (int r = 0; r < 4; ++r) {
                    const int row = (bx << 7) + wm + 16 * m + 4 * lg + r;
                    outP1[(size_t)row * N + col] = acc[m][n][r];
                }
            }
        }
    }
}

// ---------- flash attention: bh-major grid, diag-only mask, defer-max,
// cvt_pk softmax pack, contiguous permuted-V b128 fragments ----------
__global__ __launch_bounds__(256) void attn_k(const uint16_t* __restrict__ qkv,
                                              const uint16_t* __restrict__ vT,
                                              uint16_t* __restrict__ o) {
    __shared__ uint16_t Kb[2][64 * 64];
    __shared__ uint16_t Vb[2][64 * 64];
    const int tid = threadIdx.x;
    const int wave = tid >> 6, lane = tid & 63;
    const int lg = lane >> 4, lr = lane & 15, lr7 = lr & 7;
    const int bh = blockIdx.x, b = bh >> 4, h = bh & 15;
    const size_t rs = 3 * Cdim;
    const uint16_t* qp = qkv + (size_t)b * Tdim * rs + (size_t)h * HDdim;
    const uint16_t* kp = qp + Cdim;
    const uint16_t* vtp = vT + (size_t)bh * HDdim * Tdim;

    const int s0 = tid, s1 = tid + 256;
    const int r0v = s0 >> 3, c0v = ((s0 & 7) ^ (r0v & 7)) << 3;
    const int r1v = s1 >> 3, c1v = ((s1 & 7) ^ (r1v & 7)) << 3;
    const int db0 = wave * 512, db1 = 2048 + wave * 512;

#define STAGE(bufi, kvb)                                                        \
    do {                                                                        \
        gload_lds16(kp + (size_t)((kvb) + r0v) * rs + c0v, &Kb[bufi][db0]);     \
        gload_lds16(kp + (size_t)((kvb) + r1v) * rs + c1v, &Kb[bufi][db1]);     \
        gload_lds16(vtp + (size_t)r0v * Tdim + (kvb) + c0v, &Vb[bufi][db0]);    \
        gload_lds16(vtp + (size_t)r1v * Tdim + (kvb) + c1v, &Vb[bufi][db1]);    \
    } while (0)

    const int tiles[2] = {(int)blockIdx.y, 31 - (int)blockIdx.y};

    for (int ti = 0; ti < 2; ++ti) {
        const int tx = tiles[ti];
        const int q0 = tx << 6;
        const int nch = tx + 1;
        const int qrow = q0 + 16 * wave + lr;

        short8 qf[2];
#pragma unroll
        for (int c = 0; c < 2; ++c) {
            short8 raw = *(const short8*)(qp + (size_t)qrow * rs + 32 * c + 8 * lg);
#pragma unroll
            for (int j = 0; j < 8; ++j)
                qf[c][j] = (short)f2bf(bf2f((uint16_t)raw[j]) * 0.125f);
        }

        float m_run = -__builtin_inff(), l_run = 0.f;
        f32x4 oacc[4];
#pragma unroll
        for (int t = 0; t < 4; ++t) oacc[t] = (f32x4){0.f, 0.f, 0.f, 0.f};

        STAGE(0, 0);
        __syncthreads();
        int cur = 0;
        for (int ch = 0; ch < nch; ++ch) {
            if (ch + 1 < nch) STAGE(cur ^ 1, 64 * (ch + 1));
            const int kvb = 64 * ch;
            const char* Kc = (const char*)&Kb[cur][0];
            const char* Vc = (const char*)&Vb[cur][0];
            short8 kf[4][2];
#pragma unroll
            for (int u = 0; u < 4; ++u)
#pragma unroll
                for (int c = 0; c < 2; ++c)
                    kf[u][c] = *(const short8*)(Kc + (16 * u + lr) * 128 +
                                                (((lg + 4 * c) ^ lr7) << 4));
            f32x4 s4[4];
            __builtin_amdgcn_s_setprio(1);
#pragma unroll
            for (int u = 0; u < 4; ++u) {
                f32x4 z = (f32x4){0.f, 0.f, 0.f, 0.f};
                z = __builtin_amdgcn_mfma_f32_16x16x32_bf16(kf[u][0], qf[0], z, 0, 0, 0);
                z = __builtin_amdgcn_mfma_f32_16x16x32_bf16(kf[u][1], qf[1], z, 0, 0, 0);
                s4[u] = z;
            }
            __builtin_amdgcn_s_setprio(0);
            // ---- softmax: mask only the diagonal chunk ----
            float p[4][4];
            float mx;
            if (ch + 1 == nch) {
                mx = -__builtin_inff();
#pragma unroll
                for (int u = 0; u < 4; ++u)
#pragma unroll
                    for (int r = 0; r < 4; ++r) {
                        int kv = kvb + 16 * u + 4 * lg + r;
                        float sv = (kv <= qrow) ? s4[u][r] : -__builtin_inff();
                        p[u][r] = sv;
                        mx = fmaxf(mx, sv);
                    }
            } else {
#pragma unroll
                for (int u = 0; u < 4; ++u)
#pragma unroll
                    for (int r = 0; r < 4; ++r) p[u][r] = s4[u][r];
                f32x4 m4;
#pragma unroll
                for (int r = 0; r < 4; ++r)
                    m4[r] = fmaxf(fmaxf(s4[0][r], s4[1][r]), fmaxf(s4[2][r], s4[3][r]));
                mx = fmaxf(fmaxf(m4[0], m4[1]), fmaxf(m4[2], m4[3]));
            }
            mx = fmaxf(mx, __shfl_xor(mx, 16));
            mx = fmaxf(mx, __shfl_xor(mx, 32));
            // ---- defer-max (T13, THR=8) ----
            if (!__all(mx <= m_run + 8.f)) {
                const float m_new = fmaxf(m_run, mx);
                const float alpha = __expf(m_run - m_new);
#pragma unroll
                for (int t = 0; t < 4; ++t)
#pragma unroll
                    for (int r = 0; r < 4; ++r) oacc[t][r] *= alpha;
                l_run *= alpha;
                m_run = m_new;
            }
            float ps = 0.f;
#pragma unroll
            for (int u = 0; u < 4; ++u)
#pragma unroll
                for (int r = 0; r < 4; ++r) {
                    float e = __expf(p[u][r] - m_run);
                    p[u][r] = e; ps += e;
                }
            ps += __shfl_xor(ps, 16);
            ps += __shfl_xor(ps, 32);
            l_run += ps;
            // ---- P -> bf16 via v_cvt_pk ----
            short8 pb[2];
#pragma unroll
            for (int hh = 0; hh < 2; ++hh) {
                union { uint32_t w[4]; short8 v; } q_;
                q_.w[0] = cvtpk(p[2 * hh][0], p[2 * hh][1]);
                q_.w[1] = cvtpk(p[2 * hh][2], p[2 * hh][3]);
                q_.w[2] = cvtpk(p[2 * hh + 1][0], p[2 * hh + 1][1]);
                q_.w[3] = cvtpk(p[2 * hh + 1][2], p[2 * hh + 1][3]);
                pb[hh] = q_.v;
            }
            // ---- PV: permuted V layout -> one b128 per fragment ----
            __builtin_amdgcn_s_setprio(1);
#pragma unroll
            for (int t = 0; t < 4; ++t) {
                const int vbase = (16 * t + lr) * 128;
                f32x4 oa = oacc[t];
#pragma unroll
                for (int hh = 0; hh < 2; ++hh) {
                    short8 vf = *(const short8*)(Vc + vbase + (((4 * hh + lg) ^ lr7) << 4));
                    oa = __builtin_amdgcn_mfma_f32_16x16x32_bf16(vf, pb[hh], oa, 0, 0, 0);
                }
                oacc[t] = oa;
            }
            __builtin_amdgcn_s_setprio(0);
            __syncthreads();
            cur ^= 1;
        }
        // epilogue: packed bf16, 8B stores
        const float inv = 1.f / l_run;
        uint16_t* orow = o + (size_t)(b * Tdim + qrow) * Cdim + h * HDdim;
#pragma unroll
        for (int t = 0; t < 4; ++t) {
            u32x2 wv;
            wv[0] = cvtpk(oacc[t][0] * inv, oacc[t][1] * inv);
            wv[1] = cvtpk(oacc[t][2] * inv, oacc[t][3] * inv);
            *(u32x2*)(orow + 16 * t + 4 * lg) = wv;
        }
        __syncthreads();
    }
#undef STAGE
}

// ---------- LayerNorm over rows of 1024: in (+ up to 3 partials) summed ----------
__global__ __launch_bounds__(256) void ln_k(const float* __restrict__ in,
                                            const float* __restrict__ in2,
                                            const float* __restrict__ in3,
                                            const float* __restrict__ in4,
                                            const float* __restrict__ g,
                                            const float* __restrict__ be,
                                            float* __restrict__ outF,
                                            uint16_t* __restrict__ outB) {
    const int row = blockIdx.x, tid = threadIdx.x;
    const size_t base = (size_t)row * Cdim + tid * 4;
    f32x4 xv = *(const f32x4*)(in + base);
    if (in2) {
        f32x4 yv = *(const f32x4*)(in2 + base);
#pragma unroll
        for (int j = 0; j < 4; ++j) xv[j] += yv[j];
    }
    if (in3) {
        f32x4 yv = *(const f32x4*)(in3 + base);
#pragma unroll
        for (int j = 0; j < 4; ++j) xv[j] += yv[j];
    }
    if (in4) {
        f32x4 yv = *(const f32x4*)(in4 + base);
#pragma unroll
        for (int j = 0; j < 4; ++j) xv[j] += yv[j];
    }
    float s = xv[0] + xv[1] + xv[2] + xv[3];
    float q = xv[0] * xv[0] + xv[1] * xv[1] + xv[2] * xv[2] + xv[3] * xv[3];
#pragma unroll
    for (int off = 1; off < 64; off <<= 1) { s += __shfl_xor(s, off); q += __shfl_xor(q, off); }
    __shared__ float sm[4], sq[4];
    if ((tid & 63) == 0) { sm[tid >> 6] = s; sq[tid >> 6] = q; }
    __syncthreads();
    s = sm[0] + sm[1] + sm[2] + sm[3];
    q = sq[0] + sq[1] + sq[2] + sq[3];
    const float mu = s * (1.f / 1024.f);
    const float var = q * (1.f / 1024.f) - mu * mu;
    const float rstd = rsqrtf(var + 1e-5f);
#pragma unroll
    for (int j = 0; j < 4; ++j) {
        int col = tid * 4 + j;
        float y = (xv[j] - mu) * rstd * g[col] + be[col];
        if (outF) outF[(size_t)row * Cdim + col] = y;
        if (outB) outB[(size_t)row * Cdim + col] = f2bf(y);
    }
}

// ---------- launch ----------
extern "C" void kernel_launch(void* const* d_in, const int* in_sizes, int n_in,
                              void* d_out, int out_size, void* d_ws, size_t ws_size,
                              hipStream_t stream) {
    const float* x   = (const float*)d_in[0];
    const float* Wq  = (const float*)d_in[1];
    const float* Wk  = (const float*)d_in[2];
    const float* Wv  = (const float*)d_in[3];
    const float* Wp  = (const float*)d_in[4];
    const float* bp  = (const float*)d_in[5];
    const float* W1  = (const float*)d_in[6];
    const float* b1  = (const float*)d_in[7];
    const float* W2  = (const float*)d_in[8];
    const float* b2  = (const float*)d_in[9];
    const float* g1  = (const float*)d_in[10];
    const float* be1 = (const float*)d_in[11];
    const float* g2  = (const float*)d_in[12];
    const float* be2 = (const float*)d_in[13];
    float* out = (float*)d_out;

    // workspace layout (112 MB), live-range aliased (same as r6-r8):
    char* ws = (char*)d_ws;
    uint16_t* qkv   = (uint16_t*)(ws + 0);
    float*    P1p   = (float*)   (ws + 0);
    uint16_t* h1    = (uint16_t*)(ws + 0);
    uint16_t* obuf  = (uint16_t*)(ws + 25165824);
    uint16_t* xb    = (uint16_t*)(ws + 33554432);
    uint16_t* vT    = (uint16_t*)(ws + 33554432);
    uint16_t* x1b   = (uint16_t*)(ws + 33554432);
    float*    Q2    = (float*)   (ws + 33554432);
    uint16_t* wqkv  = (uint16_t*)(ws + 41943040);
    uint16_t* wpt   = (uint16_t*)(ws + 48234496);
    float*    resid = (float*)   (ws + 50331648);
    float*    Q1    = (float*)   (ws + 50331648);
    float*    x1f   = (float*)   (ws + 67108864);
    uint16_t* w1t   = (uint16_t*)(ws + 83886080);
    uint16_t* w2t   = (uint16_t*)(ws + 92274688);
    float*    Q3    = (float*)   (ws + 100663296);

    // step 1: pack / cast
    cast4_k<<<4096, 256, 0, stream>>>(x, xb);
    transpose_tile<<<dim3(32, 2, 16), dim3(32, 8), 0, stream>>>(Wq, wqkv,           1024, 64, 65536, 65536);
    transpose_tile<<<dim3(32, 2, 16), dim3(32, 8), 0, stream>>>(Wk, wqkv + 1048576, 1024, 64, 65536, 65536);
    transpose_tile<<<dim3(32, 2, 16), dim3(32, 8), 0, stream>>>(Wv, wqkv + 2097152, 1024, 64, 65536, 65536);
    transpose_tile<<<dim3(32, 32, 1),  dim3(32, 8), 0, stream>>>(Wp, wpt, 1024, 1024, 0, 0);
    transpose_tile<<<dim3(32, 128, 1), dim3(32, 8), 0, stream>>>(W1, w1t, 1024, 4096, 0, 0);
    transpose_tile<<<dim3(128, 32, 1), dim3(32, 8), 0, stream>>>(W2, w2t, 4096, 1024, 0, 0);

    // step 2: QKV projection, 256^2 pipeline (192 blocks)
    gemm8_k<false, false, false, false><<<dim3(16, 12, 1), 512, 0, stream>>>(
        xb, wqkv, Cdim, Cdim, nullptr, qkv, nullptr, nullptr,
        nullptr, nullptr, nullptr, 3 * Cdim);
    // step 3: V^T pack (kv-permuted within 32-blocks)
    vtrans_k<<<dim3(64, 2, 32), dim3(32, 8), 0, stream>>>(qkv, vT);
    // step 4: attention (bh-major grid for XCD L2 locality)
    attn_k<<<dim3(32, 16), 256, 0, stream>>>(qkv, vT, obuf);
    // step 5: output projection, 128^2 split-K=2 (512 blocks)
    gemm_k<true, false, true, true><<<dim3(32, 8, 2), 256, 0, stream>>>(
        obuf, wpt, Cdim, Cdim / 2, resid, nullptr, bp, x, P1p, Cdim);
    // step 6: LN1 over (resid + P1p) -> x1f (fp32) + x1b (bf16)
    ln_k<<<Mdim, 256, 0, stream>>>(resid, P1p, nullptr, nullptr, g1, be1, x1f, x1b);
    // step 7: FFN1 relu(x1 @ W1 + b1) -> h1, 256^2 pipeline (256 blocks = 1/CU)
    gemm8_k<true, true, false, false><<<dim3(16, 16, 1), 512, 0, stream>>>(
        x1b, w1t, Cdim, Cdim, nullptr, h1, b1, nullptr,
        nullptr, nullptr, nullptr, FFdim);
    // step 8: FFN2, 256^2 pipeline split-K=4 (256 blocks = 1/CU, Kp=1024):
    gemm8_k<true, false, true, true><<<dim3(16, 4, 4), 512, 0, stream>>>(
        h1, w2t, FFdim, FFdim / 4, x1f, nullptr, b2, x1f,
        Q1, Q2, Q3, Cdim);
    // step 9: LN2 over (x1f + Q1 + Q2 + Q3) -> out
    ln_k<<<Mdim, 256, 0, stream>>>(x1f, Q1, Q2, Q3, g2, be2, out, nullptr);
}